// Round 13
// baseline (675.867 us; speedup 1.0000x reference)
//
#include <hip/hip_runtime.h>
#include <math.h>

// KERNEL_WIDTH = sqrt(9/pi) = 1.6925687506432297
#define KW2_F  2.8647889756541161f   // (9/pi)
#define KW_INV 0.5908179502964271f   // 1/KW
#define RW_F   1.6926f               // slightly >= KW (safe superset bound)

#define NBIN_SET 4096   // position-major 16x16, slope-minor 4x4, per LOR set
#define TPB      1024   // slab-kernel block size (2 blocks/CU -> 32 waves/CU)
#define MAXL     3      // LORs per thread in slab kernel
#define KG       16     // k-slices per block
#define KGC      8      // 128 / KG
#define TROW     132    // 128+4: multiple of 4 keeps float4 staging 16B-aligned

typedef __attribute__((ext_vector_type(2))) float f2;

__device__ __forceinline__ float fast_sqrtf(float x) {
    return __builtin_amdgcn_sqrtf(x);   // raw v_sqrt_f32, ~1 ulp
}

// weight pair: w = max(0, 1 - sqrt(d2)/KW), elementwise on 2 taps
__device__ __forceinline__ f2 wpair(f2 d2) {
    f2 s;
    s.x = fast_sqrtf(d2.x);
    s.y = fast_sqrtf(d2.y);
    f2 w = 1.0f - s * KW_INV;          // vector-scalar elementwise
    w.x = fmaxf(w.x, 0.0f);
    w.y = fmaxf(w.y, 0.0f);
    return w;
}

// ---------------------------------------------------------------------------
// Slab projection kernel. G == 128 only (gated on host).
//
// Geometry:
//   x-set: walks orig axis1; u = orig0 (L[1],L[4]), v = orig2 (L[0],L[3]).
//          Slab = image[:, k, :] (rows of 512 B, coalesced).
//   y-set: walks orig axis2; u = orig0 (L[1],L[4]), v = orig1 (L[0],L[3]).
//   z-set: walks orig axis2; u = orig0 (L[0],L[3]), v = orig1 (L[1],L[4]).
//          y/z slab = Px[k] plane (contiguous 64 KB).
//
// Inner loop: FIXED 4x4 window at (ceil(u-RW), ceil(v-RW)); w>0 disk diameter
// 2*KW = 3.385 < 4 -> covers every reference tap with w>0; w clamps at 0 for
// the rest -> identical sum. Tap (3,3) is provably w==0 (du3^2 >= 1.709,
// dv3^2 >= 1.709, sum 3.42 > 9/pi) and is skipped -> 15 taps.
// Output: acc*step atomicAdd'ed into out[orig_i] (out zeroed beforehand;
// addition order across the 8 k-groups varies -> ulp-level nondeterminism).
// ---------------------------------------------------------------------------
__global__ __launch_bounds__(TPB, 2)
void proj_slab(const float* __restrict__ img,
               const float* __restrict__ Px,
               const float* __restrict__ xl,
               const float* __restrict__ yl,
               const float* __restrict__ zl,
               const float* __restrict__ center,
               const float* __restrict__ size_,
               const unsigned* __restrict__ perm,
               float* __restrict__ out,
               int nx, int ny, int nz, int Sx, int Sb)
{
    const int G = 128, G2 = 128 * 128;
    __shared__ float tile[128 * TROW];   // 67.6 KB -> 2 blocks/CU

    const int b   = blockIdx.x;
    const int tid = threadIdx.x;
    const int nB  = ny + nz;

    int kg, lo, hi, isA;
    if (b < KGC * Sx) {
        isA = 1; kg = b / Sx;
        const int sp = b % Sx;
        const int c  = (nx + Sx - 1) / Sx;
        lo = sp * c; hi = min(nx, lo + c);
    } else {
        isA = 0;
        const int bb = b - KGC * Sx;
        kg = bb / Sb;
        const int sp = bb % Sb;
        const int c  = (nB + Sb - 1) / Sb;
        lo = sp * c; hi = min(nB, lo + c);
    }
    const int k0 = kg * KG;

    // block-uniform geometry (au = 0 for all sets)
    const int av = isA ? 2 : 1;
    const int aw = isA ? 1 : 2;
    const float vsu = size_[0] / (float)G, inv_vsu = 1.0f / vsu;
    const float vsv = size_[av] / (float)G, inv_vsv = 1.0f / vsv;
    const float vsw = size_[aw] / (float)G;
    const float luo = center[0]  - 0.5f * size_[0];
    const float lvo = center[av] - 0.5f * size_[av];
    const float wlo = center[aw] - 0.5f * size_[aw];

    float fu0[MAXL], fv0[MAXL], duk[MAXL], dvk[MAXL], acc[MAXL], stp[MAXL];
    int   oidx[MAXL];

#pragma unroll
    for (int l = 0; l < MAXL; ++l) {
        const int idx = lo + tid + l * TPB;
        acc[l] = 0.0f;
        if (idx < hi) {
            const float* L;
            float pu1, pu2, pv1, pv2;
            int obase;
            unsigned i;
            if (isA) {
                i = perm[idx];
                L = xl + 6 * (size_t)i;  obase = 0;
                pu1 = L[1]; pu2 = L[4]; pv1 = L[0]; pv2 = L[3];
            } else if (idx < ny) {
                i = perm[nx + idx];
                L = yl + 6 * (size_t)i;  obase = nx;
                pu1 = L[1]; pu2 = L[4]; pv1 = L[0]; pv2 = L[3];
            } else {
                i = perm[nx + idx];
                L = zl + 6 * (size_t)i;  obase = nx + ny;
                pu1 = L[0]; pu2 = L[3]; pv1 = L[1]; pv2 = L[4];
            }
            const float pw1 = L[2], pw2 = L[5];
            const float dW = pw2 - pw1;
            const float inv_dw = 1.0f / dW;
            const float dt = vsw * inv_dw;
            const float t0 = (wlo + 0.5f * vsw - pw1) * inv_dw;
            const float dU = pu2 - pu1, dV = pv2 - pv1;
            fu0[l] = (fmaf(t0, dU, pu1) - luo) * inv_vsu - 0.5f;
            fv0[l] = (fmaf(t0, dV, pv1) - lvo) * inv_vsv - 0.5f;
            duk[l] = dt * dU * inv_vsu;
            dvk[l] = dt * dV * inv_vsv;
            const float len = sqrtf(dU * dU + dV * dV + dW * dW);
            stp[l]  = vsw * len * fabsf(inv_dw);
            oidx[l] = obase + (int)i;
        } else {
            fu0[l] = -1e9f; fv0[l] = -1e9f; duk[l] = 0.0f; dvk[l] = 0.0f;
            stp[l] = 0.0f;  oidx[l] = 0;
        }
    }

    for (int kk = k0; kk < k0 + KG; ++kk) {
        __syncthreads();   // previous iteration's reads done before overwrite
        if (isA) {
#pragma unroll
            for (int it = 0; it < 4; ++it) {
                const int f = (tid + it * TPB) * 4;   // float index in plane
                const int r = f >> 7, c = f & 127;
                const float4 v = *reinterpret_cast<const float4*>(
                    img + (size_t)r * G2 + kk * G + c);
                *reinterpret_cast<float4*>(tile + r * TROW + c) = v;
            }
        } else {
#pragma unroll
            for (int it = 0; it < 4; ++it) {
                const int f = (tid + it * TPB) * 4;
                const int r = f >> 7, c = f & 127;
                const float4 v = *reinterpret_cast<const float4*>(
                    Px + (size_t)kk * G2 + f);
                *reinterpret_cast<float4*>(tile + r * TROW + c) = v;
            }
        }
        __syncthreads();

        const float fk = (float)kk;
#pragma unroll
        for (int l = 0; l < MAXL; ++l) {
            const float u = fmaf(fk, duk[l], fu0[l]);
            const float v = fmaf(fk, dvk[l], fv0[l]);
            const float fulo = ceilf(u - RW_F);
            const float fvlo = ceilf(v - RW_F);
            const int ulo = (int)fulo;
            const int vlo = (int)fvlo;
            float a = acc[l];
            if ((unsigned)ulo <= 124u && (unsigned)vlo <= 124u) {
                // interior fast path: straight-line 15 taps, uniform lanes
                const float du0 = fulo - u, dv0 = fvlo - v;
                float du2[4], dv2[4];
#pragma unroll
                for (int r = 0; r < 4; ++r) {
                    const float dr = du0 + (float)r; du2[r] = dr * dr;
                    const float dc = dv0 + (float)r; dv2[r] = dc * dc;
                }
                const float* tp = tile + (ulo * TROW + vlo);
                f2 accp = {0.0f, 0.0f};
#pragma unroll
                for (int r = 0; r < 3; ++r) {
                    const f2 d2a = {du2[r] + dv2[0], du2[r] + dv2[1]};
                    const f2 d2b = {du2[r] + dv2[2], du2[r] + dv2[3]};
                    const f2 wa = wpair(d2a);
                    const f2 wb = wpair(d2b);
                    const f2 va = {tp[r * TROW + 0], tp[r * TROW + 1]};
                    const f2 vb = {tp[r * TROW + 2], tp[r * TROW + 3]};
                    accp += wa * va;
                    accp += wb * vb;
                }
                {   // row 3: taps (3,0),(3,1),(3,2); (3,3) provably w==0
                    const f2 d2a = {du2[3] + dv2[0], du2[3] + dv2[1]};
                    const f2 wa = wpair(d2a);
                    const f2 va = {tp[3 * TROW + 0], tp[3 * TROW + 1]};
                    accp += wa * va;
                    const float d2c = du2[3] + dv2[2];
                    const float wc =
                        fmaxf(0.0f, fmaf(-fast_sqrtf(d2c), KW_INV, 1.0f));
                    a = fmaf(wc, tp[3 * TROW + 2], a);
                }
                acc[l] = a + accp.x + accp.y;
            } else if (u > -RW_F && u < 127.0f + RW_F &&
                       v > -RW_F && v < 127.0f + RW_F) {
                // edge path: masked taps (rare)
#pragma unroll
                for (int r = 0; r < 4; ++r) {
                    const int ju = ulo + r;
                    const float dd = (float)ju - u;
                    const float dd2 = dd * dd;
                    const int rb = min(max(ju, 0), 127) * TROW;
                    const bool rok = (unsigned)ju < 128u;
#pragma unroll
                    for (int c = 0; c < 4; ++c) {
                        const int jv = vlo + c;
                        const float dvv = (float)jv - v;
                        const float d2 = fmaf(dvv, dvv, dd2);
                        float w =
                            fmaxf(0.0f, fmaf(-fast_sqrtf(d2), KW_INV, 1.0f));
                        if (!(rok && (unsigned)jv < 128u)) w = 0.0f;
                        a = fmaf(w, tile[rb + min(max(jv, 0), 127)], a);
                    }
                }
                acc[l] = a;
            }
        }
    }

#pragma unroll
    for (int l = 0; l < MAXL; ++l) {
        const int idx = lo + tid + l * TPB;
        if (idx < hi)
            atomicAdd(&out[oidx[l]], acc[l] * stp[l]);
    }
}

// Zero hist bins and the output buffer (out is 0xAA-poisoned by the harness).
__global__ __launch_bounds__(256)
void zero_kernel(unsigned* __restrict__ bins, int nbins,
                 float* __restrict__ out, int nout)
{
    const int t = blockIdx.x * 256 + threadIdx.x;
    if (t < nbins) bins[t] = 0u;
    else if (t < nbins + nout) out[t - nbins] = 0.0f;
}

// ---------------------------------------------------------------------------
// Counting sort: position-major 16x16 on transverse midpoint (tile locality),
// slope-minor 4x4.
// ---------------------------------------------------------------------------
__device__ __forceinline__ int lor_key(const float* __restrict__ L)
{
    const float m0 = 0.5f * (L[0] + L[3]);
    const float m1 = 0.5f * (L[1] + L[4]);
    const float invdz = 1.0f / (L[5] - L[2]);
    const float sl0 = (L[3] - L[0]) * invdz;
    const float sl1 = (L[4] - L[1]) * invdz;
    const int qp0 = min(15, max(0, (int)((m0 + 60.0f) * 0.13333334f)));
    const int qp1 = min(15, max(0, (int)((m1 + 60.0f) * 0.13333334f)));
    const int qs0 = min(3,  max(0, (int)((sl0 + 0.75f) * 2.6666667f)));
    const int qs1 = min(3,  max(0, (int)((sl1 + 0.75f) * 2.6666667f)));
    return (((qp0 << 4) | qp1) << 4) | (qs0 << 2) | qs1;
}

__global__ __launch_bounds__(256)
void hist_kernel(const float* __restrict__ xlp, const float* __restrict__ ylp,
                 const float* __restrict__ zlp,
                 int nx, int ny, int nz, unsigned* __restrict__ hist)
{
    const int t = blockIdx.x * 256 + threadIdx.x;
    const float* L; int set;
    if (t < nx)                { L = xlp + 6 * (size_t)t;              set = 0; }
    else if (t < nx + ny)      { L = ylp + 6 * (size_t)(t - nx);       set = 1; }
    else if (t < nx + ny + nz) { L = zlp + 6 * (size_t)(t - nx - ny);  set = 2; }
    else return;
    atomicAdd(&hist[set * NBIN_SET + lor_key(L)], 1u);
}

// Exclusive scan of each set's 4096 bins. One 1024-thread block per set.
__global__ __launch_bounds__(1024)
void scan_bins(const unsigned* __restrict__ hist, unsigned* __restrict__ offs)
{
    __shared__ unsigned part[1024];
    const int set = blockIdx.x;
    const unsigned* h = hist + set * NBIN_SET;
    unsigned* o = offs + set * NBIN_SET;
    const int t = threadIdx.x;

    unsigned loc[4];
    unsigned run = 0;
#pragma unroll
    for (int k = 0; k < 4; ++k) { loc[k] = run; run += h[t * 4 + k]; }
    part[t] = run;
    __syncthreads();
    for (int off = 1; off < 1024; off <<= 1) {
        const unsigned v = (t >= off) ? part[t - off] : 0u;
        __syncthreads();
        part[t] += v;
        __syncthreads();
    }
    const unsigned base = (t == 0) ? 0u : part[t - 1];
#pragma unroll
    for (int k = 0; k < 4; ++k) o[t * 4 + k] = base + loc[k];
}

__global__ __launch_bounds__(256)
void scatter_kernel(const float* __restrict__ xlp, const float* __restrict__ ylp,
                    const float* __restrict__ zlp,
                    int nx, int ny, int nz,
                    unsigned* __restrict__ offs, unsigned* __restrict__ perm)
{
    const int t = blockIdx.x * 256 + threadIdx.x;
    const float* L; int set, i, base;
    if (t < nx)                { L = xlp + 6 * (size_t)t;             set = 0; i = t;            base = 0;       }
    else if (t < nx + ny)      { L = ylp + 6 * (size_t)(t - nx);      set = 1; i = t - nx;       base = nx;      }
    else if (t < nx + ny + nz) { L = zlp + 6 * (size_t)(t - nx - ny); set = 2; i = t - nx - ny;  base = nx + ny; }
    else return;
    const unsigned pos = atomicAdd(&offs[set * NBIN_SET + lor_key(L)], 1u);
    perm[base + pos] = (unsigned)i;
}

// ---------------------------------------------------------------------------
// Middle-tier fallback (cooperative gather path): 32 lanes per LOR.
// ---------------------------------------------------------------------------
__device__ __forceinline__
float tor_chunk(const float* __restrict__ img,
                float fx0, float fy0, float dfx, float dfy,
                int k0, int n0, int n1, int s0, int s1)
{
    float fx[4], fy[4];
#pragma unroll
    for (int j = 0; j < 4; ++j) {
        fx[j] = fmaf((float)(k0 + j), dfx, fx0);
        fy[j] = fmaf((float)(k0 + j), dfy, fy0);
    }
    const float fxmin = fminf(fx[0], fx[3]), fxmax = fmaxf(fx[0], fx[3]);
    const float fymin = fminf(fy[0], fy[3]), fymax = fmaxf(fy[0], fy[3]);
    const int xlo = max(0,      (int)ceilf (fxmin - RW_F));
    const int xhi = min(n0 - 1, (int)floorf(fxmax + RW_F));

    float acc0 = 0.0f, acc1 = 0.0f, acc2 = 0.0f, acc3 = 0.0f;
    const float* rowp = img + xlo * s0 + k0;
    for (int jx = xlo; jx <= xhi; ++jx, rowp += s0) {
        float ddx2[4];
#pragma unroll
        for (int j = 0; j < 4; ++j) {
            const float dxx = (float)jx - fx[j];
            ddx2[j] = dxx * dxx;
        }
        const float rowmin =
            fminf(fminf(ddx2[0], ddx2[1]), fminf(ddx2[2], ddx2[3]));
        const float rad = fast_sqrtf(fmaxf(KW2_F - rowmin, 0.0f));
        const int ylo = max(0,      (int)ceilf (fymin - rad));
        const int yhi = min(n1 - 1, (int)floorf(fymax + rad));

        const float* p = rowp + ylo * s1;
        for (int jy = ylo; jy <= yhi; ++jy, p += s1) {
            const float4 v = *reinterpret_cast<const float4*>(p);
            float wg[4];
#pragma unroll
            for (int j = 0; j < 4; ++j) {
                const float dyy = (float)jy - fy[j];
                const float d2  = fmaf(dyy, dyy, ddx2[j]);
                wg[j] = fmaxf(0.0f, fmaf(-fast_sqrtf(d2), KW_INV, 1.0f));
            }
            acc0 = fmaf(wg[0], v.x, acc0);
            acc1 = fmaf(wg[1], v.y, acc1);
            acc2 = fmaf(wg[2], v.z, acc2);
            acc3 = fmaf(wg[3], v.w, acc3);
        }
    }
    return (acc0 + acc1) + (acc2 + acc3);
}

__global__ __launch_bounds__(256)
void proj_coop(const float* __restrict__ imgZ,
               const float* __restrict__ imgX,
               const float* __restrict__ xlp,
               const float* __restrict__ ylp,
               const float* __restrict__ zlp,
               const float* __restrict__ center,
               const float* __restrict__ size_,
               const unsigned* __restrict__ perm,
               float* __restrict__ out,
               int nx, int ny, int nz,
               int nbx, int nby, int G)
{
    const int b = blockIdx.x;
    const int G2 = G * G;
    const int sub  = threadIdx.x >> 5;
    const int lane = threadIdx.x & 31;

    const float* img; const float* lors; float* op;
    int a0, a1, a2, s0, s1;

    if (b < nbx) {
        const int idx = b * 8 + sub; if (idx >= nx) return;
        const int i = (int)perm[idx];
        img = imgX; lors = xlp + 6 * (size_t)i;  op = out + i;
        a0 = 2; a1 = 0; a2 = 1;  s0 = G2; s1 = G;
    } else if (b < nbx + nby) {
        const int idx = (b - nbx) * 8 + sub; if (idx >= ny) return;
        const int i = (int)perm[nx + idx];
        img = imgZ; lors = ylp + 6 * (size_t)i;  op = out + nx + i;
        a0 = 1; a1 = 0; a2 = 2;  s0 = G; s1 = G2;
    } else {
        const int idx = (b - nbx - nby) * 8 + sub; if (idx >= nz) return;
        const int i = (int)perm[nx + ny + idx];
        img = imgZ; lors = zlp + 6 * (size_t)i;  op = out + nx + ny + i;
        a0 = 0; a1 = 1; a2 = 2;  s0 = G2; s1 = G;
    }

    const float S0 = size_[a0], S1 = size_[a1], S2 = size_[a2];
    const float vs0 = S0 / (float)G, vs1 = S1 / (float)G, vs2 = S2 / (float)G;
    const float lo0 = center[a0] - 0.5f * S0;
    const float lo1 = center[a1] - 0.5f * S1;
    const float lo2 = center[a2] - 0.5f * S2;
    const float inv_vs0 = 1.0f / vs0, inv_vs1 = 1.0f / vs1;

    const float p1x = lors[0], p1y = lors[1], p1z = lors[2];
    const float p2x = lors[3], p2y = lors[4], p2z = lors[5];
    const float dx = p2x - p1x, dy = p2y - p1y, dz = p2z - p1z;
    const float len = sqrtf(dx * dx + dy * dy + dz * dz);
    const float inv_dz = 1.0f / dz;
    const float step = vs2 * len * fabsf(inv_dz);

    const float t0  = (lo2 + 0.5f * vs2 - p1z) * inv_dz;
    const float dt  = vs2 * inv_dz;
    const float fx0 = (fmaf(t0, dx, p1x) - lo0) * inv_vs0 - 0.5f;
    const float fy0 = (fmaf(t0, dy, p1y) - lo1) * inv_vs1 - 0.5f;
    const float dfx = dt * dx * inv_vs0;
    const float dfy = dt * dy * inv_vs1;

    float partialv = 0.0f;
    const int nchunks = G >> 2;
    for (int c = lane; c < nchunks; c += 32)
        partialv += tor_chunk(img, fx0, fy0, dfx, dfy, 4 * c, G, G, s0, s1);

#pragma unroll
    for (int m = 16; m >= 1; m >>= 1)
        partialv += __shfl_xor(partialv, m);

    if (lane == 0) *op = partialv * step;
}

// Scalar fallback (any G), one thread per LOR.
__device__ __forceinline__
float tor_lor_s(const float* __restrict__ img,
                const float* __restrict__ L,
                float lo0, float lo1, float lo2,
                float vs0, float vs1, float vs2,
                int n0, int n1, int n2, int s0, int s1, int s2)
{
    const float inv_vs0 = 1.0f / vs0, inv_vs1 = 1.0f / vs1;
    const float p1x = L[0], p1y = L[1], p1z = L[2];
    const float p2x = L[3], p2y = L[4], p2z = L[5];
    const float dx = p2x - p1x, dy = p2y - p1y, dz = p2z - p1z;
    const float len = sqrtf(dx * dx + dy * dy + dz * dz);
    const float inv_dz = 1.0f / dz;
    const float step = vs2 * len * fabsf(inv_dz);

    float acc_total = 0.0f;
    for (int k = 0; k < n2; ++k) {
        const float zc = lo2 + ((float)k + 0.5f) * vs2;
        const float t  = (zc - p1z) * inv_dz;
        const float fx = (fmaf(t, dx, p1x) - lo0) * inv_vs0 - 0.5f;
        const float fy = (fmaf(t, dy, p1y) - lo1) * inv_vs1 - 0.5f;
        const int ix = (int)rintf(fx);
        const int iy = (int)rintf(fy);
        const int kb = k * s2;
        float acc = 0.0f;
#pragma unroll
        for (int o0 = -2; o0 <= 2; ++o0) {
            const int jx = ix + o0;
            if ((unsigned)jx >= (unsigned)n0) continue;
            const float dxx  = (float)jx - fx;
            const float ddx2 = dxx * dxx;
            if (ddx2 >= KW2_F) continue;
            const int xb = jx * s0 + kb;
#pragma unroll
            for (int o1 = -2; o1 <= 2; ++o1) {
                const int jy = iy + o1;
                if ((unsigned)jy >= (unsigned)n1) continue;
                const float dyy = (float)jy - fy;
                const float d2  = fmaf(dyy, dyy, ddx2);
                if (d2 < KW2_F) {
                    const float w = fmaf(-fast_sqrtf(d2), KW_INV, 1.0f);
                    acc = fmaf(w, img[xb + jy * s1], acc);
                }
            }
        }
        acc_total += acc;
    }
    return acc_total * step;
}

__global__ __launch_bounds__(256)
void proj_fallback(const float* __restrict__ img,
                   const float* __restrict__ xlp,
                   const float* __restrict__ ylp,
                   const float* __restrict__ zlp,
                   const float* __restrict__ center,
                   const float* __restrict__ size_,
                   float* __restrict__ out,
                   int nx, int ny, int nz,
                   int nbx, int nby, int G)
{
    const int b = blockIdx.x;
    const int G2 = G * G;
    const float* lors; float* op;
    int a0, a1, a2, s0, s1, s2;

    if (b < nbx) {
        const int i = b * 256 + threadIdx.x; if (i >= nx) return;
        lors = xlp + 6 * (size_t)i;  op = out + i;
        a0 = 2; a1 = 0; a2 = 1;  s0 = 1; s1 = G2; s2 = G;
    } else if (b < nbx + nby) {
        const int i = (b - nbx) * 256 + threadIdx.x; if (i >= ny) return;
        lors = ylp + 6 * (size_t)i;  op = out + nx + i;
        a0 = 1; a1 = 0; a2 = 2;  s0 = G; s1 = G2; s2 = 1;
    } else {
        const int i = (b - nbx - nby) * 256 + threadIdx.x; if (i >= nz) return;
        lors = zlp + 6 * (size_t)i;  op = out + nx + ny + i;
        a0 = 0; a1 = 1; a2 = 2;  s0 = G2; s1 = G; s2 = 1;
    }

    const float S0 = size_[a0], S1 = size_[a1], S2 = size_[a2];
    const float vs0 = S0 / (float)G, vs1 = S1 / (float)G, vs2 = S2 / (float)G;
    *op = tor_lor_s(img, lors,
                    center[a0] - 0.5f * S0, center[a1] - 0.5f * S1,
                    center[a2] - 0.5f * S2,
                    vs0, vs1, vs2, G, G, G, s0, s1, s2);
}

// 2D transpose in[R][C] -> out[C][R]; Px[a,i0,i1] = image[i0,i1,a].
__global__ __launch_bounds__(256)
void transpose_RC(const float* __restrict__ in, float* __restrict__ outp,
                  int R, int C)
{
    __shared__ float tile[32][33];
    const int rt = blockIdx.x * 32;
    const int ct = blockIdx.y * 32;
    const int tx = threadIdx.x;
    const int ty = threadIdx.y;   // block (32,8)
#pragma unroll
    for (int j = 0; j < 32; j += 8)
        tile[ty + j][tx] = in[(size_t)(rt + ty + j) * C + (ct + tx)];
    __syncthreads();
#pragma unroll
    for (int j = 0; j < 32; j += 8)
        outp[(size_t)(ct + ty + j) * R + (rt + tx)] = tile[tx][ty + j];
}

extern "C" void kernel_launch(void* const* d_in, const int* in_sizes, int n_in,
                              void* d_out, int out_size, void* d_ws, size_t ws_size,
                              hipStream_t stream)
{
    const float* img    = (const float*)d_in[0];
    const float* center = (const float*)d_in[2];
    const float* size_  = (const float*)d_in[3];
    const float* xlors  = (const float*)d_in[4];
    const float* ylors  = (const float*)d_in[5];
    const float* zlors  = (const float*)d_in[6];
    float* out = (float*)d_out;

    const int nx = in_sizes[4] / 6;
    const int ny = in_sizes[5] / 6;
    const int nz = in_sizes[6] / 6;
    const int ntot = nx + ny + nz;

    int G = (int)lround(cbrt((double)in_sizes[0]));
    const int G2 = G * G;

    // Workspace: [Px G^3 f32][hist 3*4096][offs 3*4096][perm ntot]
    const size_t pxBytes  = (size_t)G * G2 * sizeof(float);
    const int    nbins    = 3 * NBIN_SET;
    const size_t sortB    = 2 * (size_t)nbins * sizeof(unsigned)
                          + (size_t)ntot * sizeof(unsigned);
    const size_t need     = pxBytes + sortB;

    const bool slab = (G == 128) && (ws_size >= need);
    const bool coop = !slab && (G % 32 == 0) && (ws_size >= need);

    if (slab || coop) {
        float*    Px   = (float*)d_ws;
        unsigned* hist = (unsigned*)((char*)d_ws + pxBytes);
        unsigned* offs = hist + nbins;
        unsigned* perm = offs + nbins;

        transpose_RC<<<dim3(G2 / 32, G / 32), dim3(32, 8), 0, stream>>>(
            img, Px, G2, G);

        zero_kernel<<<(nbins + ntot + 255) / 256, 256, 0, stream>>>(
            hist, nbins, out, ntot);
        hist_kernel<<<(ntot + 255) / 256, 256, 0, stream>>>(
            xlors, ylors, zlors, nx, ny, nz, hist);
        scan_bins<<<3, 1024, 0, stream>>>(hist, offs);
        scatter_kernel<<<(ntot + 255) / 256, 256, 0, stream>>>(
            xlors, ylors, zlors, nx, ny, nz, offs, perm);

        if (slab) {
            const int cap = TPB * MAXL;
            const int Sx = max(1, (nx + cap - 1) / cap);
            const int Sb = max(1, (ny + nz + cap - 1) / cap);
            proj_slab<<<KGC * (Sx + Sb), TPB, 0, stream>>>(
                img, Px, xlors, ylors, zlors, center, size_, perm, out,
                nx, ny, nz, Sx, Sb);
        } else {
            const int nbx = (nx + 7) / 8;
            const int nby = (ny + 7) / 8;
            const int nbz = (nz + 7) / 8;
            proj_coop<<<nbx + nby + nbz, 256, 0, stream>>>(
                img, Px, xlors, ylors, zlors, center, size_, perm, out,
                nx, ny, nz, nbx, nby, G);
        }
    } else {
        const int nbx = (nx + 255) / 256;
        const int nby = (ny + 255) / 256;
        const int nbz = (nz + 255) / 256;
        proj_fallback<<<nbx + nby + nbz, 256, 0, stream>>>(
            img, xlors, ylors, zlors, center, size_, out,
            nx, ny, nz, nbx, nby, G);
    }
}

// Round 14
// 546.453 us; speedup vs baseline: 1.2368x; 1.2368x over previous
//
#include <hip/hip_runtime.h>
#include <math.h>

// KERNEL_WIDTH = sqrt(9/pi) = 1.6925687506432297
#define KW2_F  2.8647889756541161f   // (9/pi)
#define KW_INV 0.5908179502964271f   // 1/KW
#define RW_F   1.6926f               // slightly >= KW (safe superset bound)

#define NBIN_SET 4096   // position-major 16x16, slope-minor 4x4, per LOR set
#define TPB      1024   // slab-kernel block size (2 blocks/CU -> 32 waves/CU)
#define MAXL     3      // LORs per thread in slab kernel
#define KG       16     // k-slices per block
#define KGC      8      // 128 / KG
#define TROW     132    // 128+4: multiple of 4 keeps float4 staging 16B-aligned

typedef __attribute__((ext_vector_type(2))) float f2;

__device__ __forceinline__ float fast_sqrtf(float x) {
    return __builtin_amdgcn_sqrtf(x);   // raw v_sqrt_f32, ~1 ulp
}

// weight pair: w = max(0, 1 - sqrt(d2)/KW), elementwise on 2 taps
__device__ __forceinline__ f2 wpair(f2 d2) {
    f2 s;
    s.x = fast_sqrtf(d2.x);
    s.y = fast_sqrtf(d2.y);
    f2 w = 1.0f - s * KW_INV;          // candidate v_pk_fma_f32
    w.x = fmaxf(w.x, 0.0f);
    w.y = fmaxf(w.y, 0.0f);
    return w;
}

// ---------------------------------------------------------------------------
// Slab projection kernel. G == 128 only (gated on host).
//
// Geometry:
//   x-set: walks orig axis1; u = orig0 (L[1],L[4]), v = orig2 (L[0],L[3]).
//          Slab = image[:, k, :] (rows of 512 B, coalesced).
//   y-set: walks orig axis2; u = orig0 (L[1],L[4]), v = orig1 (L[0],L[3]).
//   z-set: walks orig axis2; u = orig0 (L[0],L[3]), v = orig1 (L[1],L[4]).
//          y/z slab = Px[k] plane (contiguous 64 KB).
//
// Inner loop: FIXED 4x4 window at (ceil(u-RW), ceil(v-RW)); w>0 disk diameter
// 2*KW = 3.385 < 4 -> covers every reference tap with w>0; w clamps at 0 for
// the rest -> identical sum. Tap (3,3) is provably w==0 (du3^2 >= 1.709,
// dv3^2 >= 1.709, sum 3.42 > 9/pi) and is skipped -> 15 taps.
// Output: per-k-group partial sums to a [KGC][ntot] buffer (coalesced),
// reduced by finalize_kernel (deterministic).
// ---------------------------------------------------------------------------
__global__ __launch_bounds__(TPB, 2)
void proj_slab(const float* __restrict__ img,
               const float* __restrict__ Px,
               const float* __restrict__ xl,
               const float* __restrict__ yl,
               const float* __restrict__ zl,
               const float* __restrict__ center,
               const float* __restrict__ size_,
               const unsigned* __restrict__ perm,
               float* __restrict__ partial,
               int nx, int ny, int nz, int Sx, int Sb)
{
    const int G = 128, G2 = 128 * 128;
    __shared__ float tile[128 * TROW];   // 67.6 KB -> 2 blocks/CU

    const int b   = blockIdx.x;
    const int tid = threadIdx.x;
    const int nB  = ny + nz;
    const int ntot = nx + nB;

    int kg, lo, hi, isA;
    if (b < KGC * Sx) {
        isA = 1; kg = b / Sx;
        const int sp = b % Sx;
        const int c  = (nx + Sx - 1) / Sx;
        lo = sp * c; hi = min(nx, lo + c);
    } else {
        isA = 0;
        const int bb = b - KGC * Sx;
        kg = bb / Sb;
        const int sp = bb % Sb;
        const int c  = (nB + Sb - 1) / Sb;
        lo = sp * c; hi = min(nB, lo + c);
    }
    const int k0 = kg * KG;

    // block-uniform geometry (au = 0 for all sets)
    const int av = isA ? 2 : 1;
    const int aw = isA ? 1 : 2;
    const float vsu = size_[0] / (float)G, inv_vsu = 1.0f / vsu;
    const float vsv = size_[av] / (float)G, inv_vsv = 1.0f / vsv;
    const float vsw = size_[aw] / (float)G;
    const float luo = center[0]  - 0.5f * size_[0];
    const float lvo = center[av] - 0.5f * size_[av];
    const float wlo = center[aw] - 0.5f * size_[aw];

    float fu0[MAXL], fv0[MAXL], duk[MAXL], dvk[MAXL], acc[MAXL];

#pragma unroll
    for (int l = 0; l < MAXL; ++l) {
        const int idx = lo + tid + l * TPB;
        acc[l] = 0.0f;
        if (idx < hi) {
            const float* L;
            float pu1, pu2, pv1, pv2;
            if (isA) {
                const unsigned i = perm[idx];
                L = xl + 6 * (size_t)i;
                pu1 = L[1]; pu2 = L[4]; pv1 = L[0]; pv2 = L[3];
            } else if (idx < ny) {
                const unsigned i = perm[nx + idx];
                L = yl + 6 * (size_t)i;
                pu1 = L[1]; pu2 = L[4]; pv1 = L[0]; pv2 = L[3];
            } else {
                const unsigned i = perm[nx + idx];
                L = zl + 6 * (size_t)i;
                pu1 = L[0]; pu2 = L[3]; pv1 = L[1]; pv2 = L[4];
            }
            const float pw1 = L[2], pw2 = L[5];
            const float inv_dw = 1.0f / (pw2 - pw1);
            const float dt = vsw * inv_dw;
            const float t0 = (wlo + 0.5f * vsw - pw1) * inv_dw;
            const float dU = pu2 - pu1, dV = pv2 - pv1;
            fu0[l] = (fmaf(t0, dU, pu1) - luo) * inv_vsu - 0.5f;
            fv0[l] = (fmaf(t0, dV, pv1) - lvo) * inv_vsv - 0.5f;
            duk[l] = dt * dU * inv_vsu;
            dvk[l] = dt * dV * inv_vsv;
        } else {
            fu0[l] = -1e9f; fv0[l] = -1e9f; duk[l] = 0.0f; dvk[l] = 0.0f;
        }
    }

    for (int kk = k0; kk < k0 + KG; ++kk) {
        __syncthreads();   // previous iteration's reads done before overwrite
        if (isA) {
#pragma unroll
            for (int it = 0; it < 4; ++it) {
                const int f = (tid + it * TPB) * 4;   // float index in plane
                const int r = f >> 7, c = f & 127;
                const float4 v = *reinterpret_cast<const float4*>(
                    img + (size_t)r * G2 + kk * G + c);
                *reinterpret_cast<float4*>(tile + r * TROW + c) = v;
            }
        } else {
#pragma unroll
            for (int it = 0; it < 4; ++it) {
                const int f = (tid + it * TPB) * 4;
                const int r = f >> 7, c = f & 127;
                const float4 v = *reinterpret_cast<const float4*>(
                    Px + (size_t)kk * G2 + f);
                *reinterpret_cast<float4*>(tile + r * TROW + c) = v;
            }
        }
        __syncthreads();

        const float fk = (float)kk;
#pragma unroll
        for (int l = 0; l < MAXL; ++l) {
            const float u = fmaf(fk, duk[l], fu0[l]);
            const float v = fmaf(fk, dvk[l], fv0[l]);
            const float fulo = ceilf(u - RW_F);
            const float fvlo = ceilf(v - RW_F);
            const int ulo = (int)fulo;
            const int vlo = (int)fvlo;
            float a = acc[l];
            if ((unsigned)ulo <= 124u && (unsigned)vlo <= 124u) {
                // interior fast path: straight-line 15 taps, uniform lanes
                const float du0 = fulo - u, dv0 = fvlo - v;
                float du2[4], dv2[4];
#pragma unroll
                for (int r = 0; r < 4; ++r) {
                    const float dr = du0 + (float)r; du2[r] = dr * dr;
                    const float dc = dv0 + (float)r; dv2[r] = dc * dc;
                }
                const float* tp = tile + (ulo * TROW + vlo);
                f2 accp = {0.0f, 0.0f};
#pragma unroll
                for (int r = 0; r < 3; ++r) {
                    const f2 d2a = {du2[r] + dv2[0], du2[r] + dv2[1]};
                    const f2 d2b = {du2[r] + dv2[2], du2[r] + dv2[3]};
                    const f2 wa = wpair(d2a);
                    const f2 wb = wpair(d2b);
                    const f2 va = {tp[r * TROW + 0], tp[r * TROW + 1]};
                    const f2 vb = {tp[r * TROW + 2], tp[r * TROW + 3]};
                    accp += wa * va;
                    accp += wb * vb;
                }
                {   // row 3: taps (3,0),(3,1),(3,2); (3,3) provably w==0
                    const f2 d2a = {du2[3] + dv2[0], du2[3] + dv2[1]};
                    const f2 wa = wpair(d2a);
                    const f2 va = {tp[3 * TROW + 0], tp[3 * TROW + 1]};
                    accp += wa * va;
                    const float d2c = du2[3] + dv2[2];
                    const float wc =
                        fmaxf(0.0f, fmaf(-fast_sqrtf(d2c), KW_INV, 1.0f));
                    a = fmaf(wc, tp[3 * TROW + 2], a);
                }
                acc[l] = a + accp.x + accp.y;
            } else if (u > -RW_F && u < 127.0f + RW_F &&
                       v > -RW_F && v < 127.0f + RW_F) {
                // edge path: masked taps (rare)
#pragma unroll
                for (int r = 0; r < 4; ++r) {
                    const int ju = ulo + r;
                    const float dd = (float)ju - u;
                    const float dd2 = dd * dd;
                    const int rb = min(max(ju, 0), 127) * TROW;
                    const bool rok = (unsigned)ju < 128u;
#pragma unroll
                    for (int c = 0; c < 4; ++c) {
                        const int jv = vlo + c;
                        const float dvv = (float)jv - v;
                        const float d2 = fmaf(dvv, dvv, dd2);
                        float w =
                            fmaxf(0.0f, fmaf(-fast_sqrtf(d2), KW_INV, 1.0f));
                        if (!(rok && (unsigned)jv < 128u)) w = 0.0f;
                        a = fmaf(w, tile[rb + min(max(jv, 0), 127)], a);
                    }
                }
                acc[l] = a;
            }
        }
    }

#pragma unroll
    for (int l = 0; l < MAXL; ++l) {
        const int idx = lo + tid + l * TPB;
        if (idx < hi) {
            const int sidx = isA ? idx : nx + idx;
            partial[(size_t)kg * ntot + sidx] = acc[l];
        }
    }
}

// Finalize: sum KGC partials, apply step, un-permute.
__global__ __launch_bounds__(256)
void finalize_kernel(const float* __restrict__ xl,
                     const float* __restrict__ yl,
                     const float* __restrict__ zl,
                     const float* __restrict__ size_,
                     const unsigned* __restrict__ perm,
                     const float* __restrict__ partial,
                     float* __restrict__ out,
                     int nx, int ny, int nz, int G)
{
    const int t = blockIdx.x * 256 + threadIdx.x;
    const int ntot = nx + ny + nz;
    if (t >= ntot) return;

    const unsigned i = perm[t];
    const float* L; int obase; float vsw;
    if (t < nx)           { L = xl + 6 * (size_t)i; obase = 0;       vsw = size_[1] / (float)G; }
    else if (t < nx + ny) { L = yl + 6 * (size_t)i; obase = nx;      vsw = size_[2] / (float)G; }
    else                  { L = zl + 6 * (size_t)i; obase = nx + ny; vsw = size_[2] / (float)G; }

    float s = 0.0f;
#pragma unroll
    for (int kg = 0; kg < KGC; ++kg) s += partial[(size_t)kg * ntot + t];

    const float dx = L[3] - L[0], dy = L[4] - L[1], dz = L[5] - L[2];
    const float len = sqrtf(dx * dx + dy * dy + dz * dz);
    out[obase + (int)i] = s * vsw * len / fabsf(dz);
}

// ---------------------------------------------------------------------------
// Counting sort: position-major 16x16 on transverse midpoint (tile locality),
// slope-minor 4x4.
// ---------------------------------------------------------------------------
__device__ __forceinline__ int lor_key(const float* __restrict__ L)
{
    const float m0 = 0.5f * (L[0] + L[3]);
    const float m1 = 0.5f * (L[1] + L[4]);
    const float invdz = 1.0f / (L[5] - L[2]);
    const float sl0 = (L[3] - L[0]) * invdz;
    const float sl1 = (L[4] - L[1]) * invdz;
    const int qp0 = min(15, max(0, (int)((m0 + 60.0f) * 0.13333334f)));
    const int qp1 = min(15, max(0, (int)((m1 + 60.0f) * 0.13333334f)));
    const int qs0 = min(3,  max(0, (int)((sl0 + 0.75f) * 2.6666667f)));
    const int qs1 = min(3,  max(0, (int)((sl1 + 0.75f) * 2.6666667f)));
    return (((qp0 << 4) | qp1) << 4) | (qs0 << 2) | qs1;
}

__global__ __launch_bounds__(256)
void zero_bins(unsigned* __restrict__ bins, int n)
{
    const int t = blockIdx.x * 256 + threadIdx.x;
    if (t < n) bins[t] = 0u;
}

__global__ __launch_bounds__(256)
void hist_kernel(const float* __restrict__ xlp, const float* __restrict__ ylp,
                 const float* __restrict__ zlp,
                 int nx, int ny, int nz, unsigned* __restrict__ hist)
{
    const int t = blockIdx.x * 256 + threadIdx.x;
    const float* L; int set;
    if (t < nx)                { L = xlp + 6 * (size_t)t;              set = 0; }
    else if (t < nx + ny)      { L = ylp + 6 * (size_t)(t - nx);       set = 1; }
    else if (t < nx + ny + nz) { L = zlp + 6 * (size_t)(t - nx - ny);  set = 2; }
    else return;
    atomicAdd(&hist[set * NBIN_SET + lor_key(L)], 1u);
}

// Exclusive scan of each set's 4096 bins. One 1024-thread block per set.
__global__ __launch_bounds__(1024)
void scan_bins(const unsigned* __restrict__ hist, unsigned* __restrict__ offs)
{
    __shared__ unsigned part[1024];
    const int set = blockIdx.x;
    const unsigned* h = hist + set * NBIN_SET;
    unsigned* o = offs + set * NBIN_SET;
    const int t = threadIdx.x;

    unsigned loc[4];
    unsigned run = 0;
#pragma unroll
    for (int k = 0; k < 4; ++k) { loc[k] = run; run += h[t * 4 + k]; }
    part[t] = run;
    __syncthreads();
    for (int off = 1; off < 1024; off <<= 1) {
        const unsigned v = (t >= off) ? part[t - off] : 0u;
        __syncthreads();
        part[t] += v;
        __syncthreads();
    }
    const unsigned base = (t == 0) ? 0u : part[t - 1];
#pragma unroll
    for (int k = 0; k < 4; ++k) o[t * 4 + k] = base + loc[k];
}

__global__ __launch_bounds__(256)
void scatter_kernel(const float* __restrict__ xlp, const float* __restrict__ ylp,
                    const float* __restrict__ zlp,
                    int nx, int ny, int nz,
                    unsigned* __restrict__ offs, unsigned* __restrict__ perm)
{
    const int t = blockIdx.x * 256 + threadIdx.x;
    const float* L; int set, i, base;
    if (t < nx)                { L = xlp + 6 * (size_t)t;             set = 0; i = t;            base = 0;       }
    else if (t < nx + ny)      { L = ylp + 6 * (size_t)(t - nx);      set = 1; i = t - nx;       base = nx;      }
    else if (t < nx + ny + nz) { L = zlp + 6 * (size_t)(t - nx - ny); set = 2; i = t - nx - ny;  base = nx + ny; }
    else return;
    const unsigned pos = atomicAdd(&offs[set * NBIN_SET + lor_key(L)], 1u);
    perm[base + pos] = (unsigned)i;
}

// ---------------------------------------------------------------------------
// Middle-tier fallback (cooperative gather path): 32 lanes per LOR.
// ---------------------------------------------------------------------------
__device__ __forceinline__
float tor_chunk(const float* __restrict__ img,
                float fx0, float fy0, float dfx, float dfy,
                int k0, int n0, int n1, int s0, int s1)
{
    float fx[4], fy[4];
#pragma unroll
    for (int j = 0; j < 4; ++j) {
        fx[j] = fmaf((float)(k0 + j), dfx, fx0);
        fy[j] = fmaf((float)(k0 + j), dfy, fy0);
    }
    const float fxmin = fminf(fx[0], fx[3]), fxmax = fmaxf(fx[0], fx[3]);
    const float fymin = fminf(fy[0], fy[3]), fymax = fmaxf(fy[0], fy[3]);
    const int xlo = max(0,      (int)ceilf (fxmin - RW_F));
    const int xhi = min(n0 - 1, (int)floorf(fxmax + RW_F));

    float acc0 = 0.0f, acc1 = 0.0f, acc2 = 0.0f, acc3 = 0.0f;
    const float* rowp = img + xlo * s0 + k0;
    for (int jx = xlo; jx <= xhi; ++jx, rowp += s0) {
        float ddx2[4];
#pragma unroll
        for (int j = 0; j < 4; ++j) {
            const float dxx = (float)jx - fx[j];
            ddx2[j] = dxx * dxx;
        }
        const float rowmin =
            fminf(fminf(ddx2[0], ddx2[1]), fminf(ddx2[2], ddx2[3]));
        const float rad = fast_sqrtf(fmaxf(KW2_F - rowmin, 0.0f));
        const int ylo = max(0,      (int)ceilf (fymin - rad));
        const int yhi = min(n1 - 1, (int)floorf(fymax + rad));

        const float* p = rowp + ylo * s1;
        for (int jy = ylo; jy <= yhi; ++jy, p += s1) {
            const float4 v = *reinterpret_cast<const float4*>(p);
            float wg[4];
#pragma unroll
            for (int j = 0; j < 4; ++j) {
                const float dyy = (float)jy - fy[j];
                const float d2  = fmaf(dyy, dyy, ddx2[j]);
                wg[j] = fmaxf(0.0f, fmaf(-fast_sqrtf(d2), KW_INV, 1.0f));
            }
            acc0 = fmaf(wg[0], v.x, acc0);
            acc1 = fmaf(wg[1], v.y, acc1);
            acc2 = fmaf(wg[2], v.z, acc2);
            acc3 = fmaf(wg[3], v.w, acc3);
        }
    }
    return (acc0 + acc1) + (acc2 + acc3);
}

__global__ __launch_bounds__(256)
void proj_coop(const float* __restrict__ imgZ,
               const float* __restrict__ imgX,
               const float* __restrict__ xlp,
               const float* __restrict__ ylp,
               const float* __restrict__ zlp,
               const float* __restrict__ center,
               const float* __restrict__ size_,
               const unsigned* __restrict__ perm,
               float* __restrict__ out,
               int nx, int ny, int nz,
               int nbx, int nby, int G)
{
    const int b = blockIdx.x;
    const int G2 = G * G;
    const int sub  = threadIdx.x >> 5;
    const int lane = threadIdx.x & 31;

    const float* img; const float* lors; float* op;
    int a0, a1, a2, s0, s1;

    if (b < nbx) {
        const int idx = b * 8 + sub; if (idx >= nx) return;
        const int i = (int)perm[idx];
        img = imgX; lors = xlp + 6 * (size_t)i;  op = out + i;
        a0 = 2; a1 = 0; a2 = 1;  s0 = G2; s1 = G;
    } else if (b < nbx + nby) {
        const int idx = (b - nbx) * 8 + sub; if (idx >= ny) return;
        const int i = (int)perm[nx + idx];
        img = imgZ; lors = ylp + 6 * (size_t)i;  op = out + nx + i;
        a0 = 1; a1 = 0; a2 = 2;  s0 = G; s1 = G2;
    } else {
        const int idx = (b - nbx - nby) * 8 + sub; if (idx >= nz) return;
        const int i = (int)perm[nx + ny + idx];
        img = imgZ; lors = zlp + 6 * (size_t)i;  op = out + nx + ny + i;
        a0 = 0; a1 = 1; a2 = 2;  s0 = G2; s1 = G;
    }

    const float S0 = size_[a0], S1 = size_[a1], S2 = size_[a2];
    const float vs0 = S0 / (float)G, vs1 = S1 / (float)G, vs2 = S2 / (float)G;
    const float lo0 = center[a0] - 0.5f * S0;
    const float lo1 = center[a1] - 0.5f * S1;
    const float lo2 = center[a2] - 0.5f * S2;
    const float inv_vs0 = 1.0f / vs0, inv_vs1 = 1.0f / vs1;

    const float p1x = lors[0], p1y = lors[1], p1z = lors[2];
    const float p2x = lors[3], p2y = lors[4], p2z = lors[5];
    const float dx = p2x - p1x, dy = p2y - p1y, dz = p2z - p1z;
    const float len = sqrtf(dx * dx + dy * dy + dz * dz);
    const float inv_dz = 1.0f / dz;
    const float step = vs2 * len * fabsf(inv_dz);

    const float t0  = (lo2 + 0.5f * vs2 - p1z) * inv_dz;
    const float dt  = vs2 * inv_dz;
    const float fx0 = (fmaf(t0, dx, p1x) - lo0) * inv_vs0 - 0.5f;
    const float fy0 = (fmaf(t0, dy, p1y) - lo1) * inv_vs1 - 0.5f;
    const float dfx = dt * dx * inv_vs0;
    const float dfy = dt * dy * inv_vs1;

    float partialv = 0.0f;
    const int nchunks = G >> 2;
    for (int c = lane; c < nchunks; c += 32)
        partialv += tor_chunk(img, fx0, fy0, dfx, dfy, 4 * c, G, G, s0, s1);

#pragma unroll
    for (int m = 16; m >= 1; m >>= 1)
        partialv += __shfl_xor(partialv, m);

    if (lane == 0) *op = partialv * step;
}

// Scalar fallback (any G), one thread per LOR.
__device__ __forceinline__
float tor_lor_s(const float* __restrict__ img,
                const float* __restrict__ L,
                float lo0, float lo1, float lo2,
                float vs0, float vs1, float vs2,
                int n0, int n1, int n2, int s0, int s1, int s2)
{
    const float inv_vs0 = 1.0f / vs0, inv_vs1 = 1.0f / vs1;
    const float p1x = L[0], p1y = L[1], p1z = L[2];
    const float p2x = L[3], p2y = L[4], p2z = L[5];
    const float dx = p2x - p1x, dy = p2y - p1y, dz = p2z - p1z;
    const float len = sqrtf(dx * dx + dy * dy + dz * dz);
    const float inv_dz = 1.0f / dz;
    const float step = vs2 * len * fabsf(inv_dz);

    float acc_total = 0.0f;
    for (int k = 0; k < n2; ++k) {
        const float zc = lo2 + ((float)k + 0.5f) * vs2;
        const float t  = (zc - p1z) * inv_dz;
        const float fx = (fmaf(t, dx, p1x) - lo0) * inv_vs0 - 0.5f;
        const float fy = (fmaf(t, dy, p1y) - lo1) * inv_vs1 - 0.5f;
        const int ix = (int)rintf(fx);
        const int iy = (int)rintf(fy);
        const int kb = k * s2;
        float acc = 0.0f;
#pragma unroll
        for (int o0 = -2; o0 <= 2; ++o0) {
            const int jx = ix + o0;
            if ((unsigned)jx >= (unsigned)n0) continue;
            const float dxx  = (float)jx - fx;
            const float ddx2 = dxx * dxx;
            if (ddx2 >= KW2_F) continue;
            const int xb = jx * s0 + kb;
#pragma unroll
            for (int o1 = -2; o1 <= 2; ++o1) {
                const int jy = iy + o1;
                if ((unsigned)jy >= (unsigned)n1) continue;
                const float dyy = (float)jy - fy;
                const float d2  = fmaf(dyy, dyy, ddx2);
                if (d2 < KW2_F) {
                    const float w = fmaf(-fast_sqrtf(d2), KW_INV, 1.0f);
                    acc = fmaf(w, img[xb + jy * s1], acc);
                }
            }
        }
        acc_total += acc;
    }
    return acc_total * step;
}

__global__ __launch_bounds__(256)
void proj_fallback(const float* __restrict__ img,
                   const float* __restrict__ xlp,
                   const float* __restrict__ ylp,
                   const float* __restrict__ zlp,
                   const float* __restrict__ center,
                   const float* __restrict__ size_,
                   float* __restrict__ out,
                   int nx, int ny, int nz,
                   int nbx, int nby, int G)
{
    const int b = blockIdx.x;
    const int G2 = G * G;
    const float* lors; float* op;
    int a0, a1, a2, s0, s1, s2;

    if (b < nbx) {
        const int i = b * 256 + threadIdx.x; if (i >= nx) return;
        lors = xlp + 6 * (size_t)i;  op = out + i;
        a0 = 2; a1 = 0; a2 = 1;  s0 = 1; s1 = G2; s2 = G;
    } else if (b < nbx + nby) {
        const int i = (b - nbx) * 256 + threadIdx.x; if (i >= ny) return;
        lors = ylp + 6 * (size_t)i;  op = out + nx + i;
        a0 = 1; a1 = 0; a2 = 2;  s0 = G; s1 = G2; s2 = 1;
    } else {
        const int i = (b - nbx - nby) * 256 + threadIdx.x; if (i >= nz) return;
        lors = zlp + 6 * (size_t)i;  op = out + nx + ny + i;
        a0 = 0; a1 = 1; a2 = 2;  s0 = G2; s1 = G; s2 = 1;
    }

    const float S0 = size_[a0], S1 = size_[a1], S2 = size_[a2];
    const float vs0 = S0 / (float)G, vs1 = S1 / (float)G, vs2 = S2 / (float)G;
    *op = tor_lor_s(img, lors,
                    center[a0] - 0.5f * S0, center[a1] - 0.5f * S1,
                    center[a2] - 0.5f * S2,
                    vs0, vs1, vs2, G, G, G, s0, s1, s2);
}

// 2D transpose in[R][C] -> out[C][R]; Px[a,i0,i1] = image[i0,i1,a].
__global__ __launch_bounds__(256)
void transpose_RC(const float* __restrict__ in, float* __restrict__ outp,
                  int R, int C)
{
    __shared__ float tile[32][33];
    const int rt = blockIdx.x * 32;
    const int ct = blockIdx.y * 32;
    const int tx = threadIdx.x;
    const int ty = threadIdx.y;   // block (32,8)
#pragma unroll
    for (int j = 0; j < 32; j += 8)
        tile[ty + j][tx] = in[(size_t)(rt + ty + j) * C + (ct + tx)];
    __syncthreads();
#pragma unroll
    for (int j = 0; j < 32; j += 8)
        outp[(size_t)(ct + ty + j) * R + (rt + tx)] = tile[tx][ty + j];
}

extern "C" void kernel_launch(void* const* d_in, const int* in_sizes, int n_in,
                              void* d_out, int out_size, void* d_ws, size_t ws_size,
                              hipStream_t stream)
{
    const float* img    = (const float*)d_in[0];
    const float* center = (const float*)d_in[2];
    const float* size_  = (const float*)d_in[3];
    const float* xlors  = (const float*)d_in[4];
    const float* ylors  = (const float*)d_in[5];
    const float* zlors  = (const float*)d_in[6];
    float* out = (float*)d_out;

    const int nx = in_sizes[4] / 6;
    const int ny = in_sizes[5] / 6;
    const int nz = in_sizes[6] / 6;
    const int ntot = nx + ny + nz;

    int G = (int)lround(cbrt((double)in_sizes[0]));
    const int G2 = G * G;

    // Workspace: [Px G^3 f32][hist 3*4096][offs 3*4096][perm ntot][partial KGC*ntot]
    const size_t pxBytes  = (size_t)G * G2 * sizeof(float);
    const int    nbins    = 3 * NBIN_SET;
    const size_t sortB    = 2 * (size_t)nbins * sizeof(unsigned)
                          + (size_t)ntot * sizeof(unsigned);
    const size_t needSlab = pxBytes + sortB + (size_t)KGC * ntot * sizeof(float);
    const size_t needCoop = pxBytes + sortB;

    const bool slab = (G == 128) && (ws_size >= needSlab);
    const bool coop = !slab && (G % 32 == 0) && (ws_size >= needCoop);

    if (slab || coop) {
        float*    Px   = (float*)d_ws;
        unsigned* hist = (unsigned*)((char*)d_ws + pxBytes);
        unsigned* offs = hist + nbins;
        unsigned* perm = offs + nbins;
        float*    part = (float*)(perm + ntot);

        transpose_RC<<<dim3(G2 / 32, G / 32), dim3(32, 8), 0, stream>>>(
            img, Px, G2, G);

        zero_bins<<<(nbins + 255) / 256, 256, 0, stream>>>(hist, nbins);
        hist_kernel<<<(ntot + 255) / 256, 256, 0, stream>>>(
            xlors, ylors, zlors, nx, ny, nz, hist);
        scan_bins<<<3, 1024, 0, stream>>>(hist, offs);
        scatter_kernel<<<(ntot + 255) / 256, 256, 0, stream>>>(
            xlors, ylors, zlors, nx, ny, nz, offs, perm);

        if (slab) {
            const int cap = TPB * MAXL;
            const int Sx = max(1, (nx + cap - 1) / cap);
            const int Sb = max(1, (ny + nz + cap - 1) / cap);
            proj_slab<<<KGC * (Sx + Sb), TPB, 0, stream>>>(
                img, Px, xlors, ylors, zlors, center, size_, perm, part,
                nx, ny, nz, Sx, Sb);
            finalize_kernel<<<(ntot + 255) / 256, 256, 0, stream>>>(
                xlors, ylors, zlors, size_, perm, part, out, nx, ny, nz, G);
        } else {
            const int nbx = (nx + 7) / 8;
            const int nby = (ny + 7) / 8;
            const int nbz = (nz + 7) / 8;
            proj_coop<<<nbx + nby + nbz, 256, 0, stream>>>(
                img, Px, xlors, ylors, zlors, center, size_, perm, out,
                nx, ny, nz, nbx, nby, G);
        }
    } else {
        const int nbx = (nx + 255) / 256;
        const int nby = (ny + 255) / 256;
        const int nbz = (nz + 255) / 256;
        proj_fallback<<<nbx + nby + nbz, 256, 0, stream>>>(
            img, xlors, ylors, zlors, center, size_, out,
            nx, ny, nz, nbx, nby, G);
    }
}

// Round 15
// 482.617 us; speedup vs baseline: 1.4004x; 1.1323x over previous
//
#include <hip/hip_runtime.h>
#include <math.h>

// KERNEL_WIDTH = sqrt(9/pi) = 1.6925687506432297
#define KW2_F  2.8647889756541161f   // (9/pi)
#define KW_INV 0.5908179502964271f   // 1/KW
#define RW_F   1.6926f               // slightly >= KW (safe superset bound)

#define NBIN_SET 4096   // entry 8x8 x exit 8x8 transverse bins, per LOR set
#define TPB      1024   // slab-kernel block size (2 blocks/CU -> 32 waves/CU)
#define MAXL     3      // LORs per thread in slab kernel
#define KG       16     // k-slices per block
#define KGC      8      // 128 / KG
// Tile row stride: bank stride B = TROW mod 32 = 12. float4 staging requires
// TROW % 4 == 0 (so B is a multiple of 4); B=12 pushes the nearest in-patch
// colliding lane offsets to (3,-4)/(5,4) vs B=4's dominant (1,-4).
#define TROW     140    // LDS = 128*140*4 = 71,680 B -> 2 blocks/CU

typedef __attribute__((ext_vector_type(2))) float f2;

__device__ __forceinline__ float fast_sqrtf(float x) {
    return __builtin_amdgcn_sqrtf(x);   // raw v_sqrt_f32, ~1 ulp
}

// weight pair: w = max(0, 1 - sqrt(d2)/KW), elementwise on 2 taps
__device__ __forceinline__ f2 wpair(f2 d2) {
    f2 s;
    s.x = fast_sqrtf(d2.x);
    s.y = fast_sqrtf(d2.y);
    f2 w = 1.0f - s * KW_INV;
    w.x = fmaxf(w.x, 0.0f);
    w.y = fmaxf(w.y, 0.0f);
    return w;
}

// ---------------------------------------------------------------------------
// Slab projection kernel. G == 128 only (gated on host).
//
// Geometry:
//   x-set: walks orig axis1; u = orig0 (L[1],L[4]), v = orig2 (L[0],L[3]).
//          Slab = image[:, k, :] (rows of 512 B, coalesced).
//   y-set: walks orig axis2; u = orig0 (L[1],L[4]), v = orig1 (L[0],L[3]).
//   z-set: walks orig axis2; u = orig0 (L[0],L[3]), v = orig1 (L[1],L[4]).
//          y/z slab = Px[k] plane (contiguous 64 KB).
//
// Inner loop: FIXED 4x4 window at (ceil(u-RW), ceil(v-RW)); w>0 disk diameter
// 2*KW = 3.385 < 4 -> covers every reference tap with w>0; w clamps at 0 for
// the rest -> identical sum. Tap (3,3) is provably w==0 (du3^2 >= 1.709,
// dv3^2 >= 1.709, sum 3.42 > 9/pi) and is skipped -> 15 taps.
// Output: per-k-group partial sums to a [KGC][ntot] buffer (coalesced),
// reduced by finalize_kernel (deterministic).
// ---------------------------------------------------------------------------
__global__ __launch_bounds__(TPB, 2)
void proj_slab(const float* __restrict__ img,
               const float* __restrict__ Px,
               const float* __restrict__ xl,
               const float* __restrict__ yl,
               const float* __restrict__ zl,
               const float* __restrict__ center,
               const float* __restrict__ size_,
               const unsigned* __restrict__ perm,
               float* __restrict__ partial,
               int nx, int ny, int nz, int Sx, int Sb)
{
    const int G = 128, G2 = 128 * 128;
    __shared__ float tile[128 * TROW];   // 71.7 KB -> 2 blocks/CU

    const int b   = blockIdx.x;
    const int tid = threadIdx.x;
    const int nB  = ny + nz;
    const int ntot = nx + nB;

    int kg, lo, hi, isA;
    if (b < KGC * Sx) {
        isA = 1; kg = b / Sx;
        const int sp = b % Sx;
        const int c  = (nx + Sx - 1) / Sx;
        lo = sp * c; hi = min(nx, lo + c);
    } else {
        isA = 0;
        const int bb = b - KGC * Sx;
        kg = bb / Sb;
        const int sp = bb % Sb;
        const int c  = (nB + Sb - 1) / Sb;
        lo = sp * c; hi = min(nB, lo + c);
    }
    const int k0 = kg * KG;

    // block-uniform geometry (au = 0 for all sets)
    const int av = isA ? 2 : 1;
    const int aw = isA ? 1 : 2;
    const float vsu = size_[0] / (float)G, inv_vsu = 1.0f / vsu;
    const float vsv = size_[av] / (float)G, inv_vsv = 1.0f / vsv;
    const float vsw = size_[aw] / (float)G;
    const float luo = center[0]  - 0.5f * size_[0];
    const float lvo = center[av] - 0.5f * size_[av];
    const float wlo = center[aw] - 0.5f * size_[aw];

    float fu0[MAXL], fv0[MAXL], duk[MAXL], dvk[MAXL], acc[MAXL];

#pragma unroll
    for (int l = 0; l < MAXL; ++l) {
        const int idx = lo + tid + l * TPB;
        acc[l] = 0.0f;
        if (idx < hi) {
            const float* L;
            float pu1, pu2, pv1, pv2;
            if (isA) {
                const unsigned i = perm[idx];
                L = xl + 6 * (size_t)i;
                pu1 = L[1]; pu2 = L[4]; pv1 = L[0]; pv2 = L[3];
            } else if (idx < ny) {
                const unsigned i = perm[nx + idx];
                L = yl + 6 * (size_t)i;
                pu1 = L[1]; pu2 = L[4]; pv1 = L[0]; pv2 = L[3];
            } else {
                const unsigned i = perm[nx + idx];
                L = zl + 6 * (size_t)i;
                pu1 = L[0]; pu2 = L[3]; pv1 = L[1]; pv2 = L[4];
            }
            const float pw1 = L[2], pw2 = L[5];
            const float inv_dw = 1.0f / (pw2 - pw1);
            const float dt = vsw * inv_dw;
            const float t0 = (wlo + 0.5f * vsw - pw1) * inv_dw;
            const float dU = pu2 - pu1, dV = pv2 - pv1;
            fu0[l] = (fmaf(t0, dU, pu1) - luo) * inv_vsu - 0.5f;
            fv0[l] = (fmaf(t0, dV, pv1) - lvo) * inv_vsv - 0.5f;
            duk[l] = dt * dU * inv_vsu;
            dvk[l] = dt * dV * inv_vsv;
        } else {
            fu0[l] = -1e9f; fv0[l] = -1e9f; duk[l] = 0.0f; dvk[l] = 0.0f;
        }
    }

    for (int kk = k0; kk < k0 + KG; ++kk) {
        __syncthreads();   // previous iteration's reads done before overwrite
        if (isA) {
#pragma unroll
            for (int it = 0; it < 4; ++it) {
                const int f = (tid + it * TPB) * 4;   // float index in plane
                const int r = f >> 7, c = f & 127;
                const float4 v = *reinterpret_cast<const float4*>(
                    img + (size_t)r * G2 + kk * G + c);
                *reinterpret_cast<float4*>(tile + r * TROW + c) = v;
            }
        } else {
#pragma unroll
            for (int it = 0; it < 4; ++it) {
                const int f = (tid + it * TPB) * 4;
                const int r = f >> 7, c = f & 127;
                const float4 v = *reinterpret_cast<const float4*>(
                    Px + (size_t)kk * G2 + f);
                *reinterpret_cast<float4*>(tile + r * TROW + c) = v;
            }
        }
        __syncthreads();

        const float fk = (float)kk;
#pragma unroll
        for (int l = 0; l < MAXL; ++l) {
            const float u = fmaf(fk, duk[l], fu0[l]);
            const float v = fmaf(fk, dvk[l], fv0[l]);
            const float fulo = ceilf(u - RW_F);
            const float fvlo = ceilf(v - RW_F);
            const int ulo = (int)fulo;
            const int vlo = (int)fvlo;
            float a = acc[l];
            if ((unsigned)ulo <= 124u && (unsigned)vlo <= 124u) {
                // interior fast path: straight-line 15 taps, uniform lanes
                const float du0 = fulo - u, dv0 = fvlo - v;
                float du2[4], dv2[4];
#pragma unroll
                for (int r = 0; r < 4; ++r) {
                    const float dr = du0 + (float)r; du2[r] = dr * dr;
                    const float dc = dv0 + (float)r; dv2[r] = dc * dc;
                }
                const float* tp = tile + (ulo * TROW + vlo);
                f2 accp = {0.0f, 0.0f};
#pragma unroll
                for (int r = 0; r < 3; ++r) {
                    const f2 d2a = {du2[r] + dv2[0], du2[r] + dv2[1]};
                    const f2 d2b = {du2[r] + dv2[2], du2[r] + dv2[3]};
                    const f2 wa = wpair(d2a);
                    const f2 wb = wpair(d2b);
                    const f2 va = {tp[r * TROW + 0], tp[r * TROW + 1]};
                    const f2 vb = {tp[r * TROW + 2], tp[r * TROW + 3]};
                    accp += wa * va;
                    accp += wb * vb;
                }
                {   // row 3: taps (3,0),(3,1),(3,2); (3,3) provably w==0
                    const f2 d2a = {du2[3] + dv2[0], du2[3] + dv2[1]};
                    const f2 wa = wpair(d2a);
                    const f2 va = {tp[3 * TROW + 0], tp[3 * TROW + 1]};
                    accp += wa * va;
                    const float d2c = du2[3] + dv2[2];
                    const float wc =
                        fmaxf(0.0f, fmaf(-fast_sqrtf(d2c), KW_INV, 1.0f));
                    a = fmaf(wc, tp[3 * TROW + 2], a);
                }
                acc[l] = a + accp.x + accp.y;
            } else if (u > -RW_F && u < 127.0f + RW_F &&
                       v > -RW_F && v < 127.0f + RW_F) {
                // edge path: masked taps (rare)
#pragma unroll
                for (int r = 0; r < 4; ++r) {
                    const int ju = ulo + r;
                    const float dd = (float)ju - u;
                    const float dd2 = dd * dd;
                    const int rb = min(max(ju, 0), 127) * TROW;
                    const bool rok = (unsigned)ju < 128u;
#pragma unroll
                    for (int c = 0; c < 4; ++c) {
                        const int jv = vlo + c;
                        const float dvv = (float)jv - v;
                        const float d2 = fmaf(dvv, dvv, dd2);
                        float w =
                            fmaxf(0.0f, fmaf(-fast_sqrtf(d2), KW_INV, 1.0f));
                        if (!(rok && (unsigned)jv < 128u)) w = 0.0f;
                        a = fmaf(w, tile[rb + min(max(jv, 0), 127)], a);
                    }
                }
                acc[l] = a;
            }
        }
    }

#pragma unroll
    for (int l = 0; l < MAXL; ++l) {
        const int idx = lo + tid + l * TPB;
        if (idx < hi) {
            const int sidx = isA ? idx : nx + idx;
            partial[(size_t)kg * ntot + sidx] = acc[l];
        }
    }
}

// Finalize: sum KGC partials, apply step, un-permute.
__global__ __launch_bounds__(256)
void finalize_kernel(const float* __restrict__ xl,
                     const float* __restrict__ yl,
                     const float* __restrict__ zl,
                     const float* __restrict__ size_,
                     const unsigned* __restrict__ perm,
                     const float* __restrict__ partial,
                     float* __restrict__ out,
                     int nx, int ny, int nz, int G)
{
    const int t = blockIdx.x * 256 + threadIdx.x;
    const int ntot = nx + ny + nz;
    if (t >= ntot) return;

    const unsigned i = perm[t];
    const float* L; int obase; float vsw;
    if (t < nx)           { L = xl + 6 * (size_t)i; obase = 0;       vsw = size_[1] / (float)G; }
    else if (t < nx + ny) { L = yl + 6 * (size_t)i; obase = nx;      vsw = size_[2] / (float)G; }
    else                  { L = zl + 6 * (size_t)i; obase = nx + ny; vsw = size_[2] / (float)G; }

    float s = 0.0f;
#pragma unroll
    for (int kg = 0; kg < KGC; ++kg) s += partial[(size_t)kg * ntot + t];

    const float dx = L[3] - L[0], dy = L[4] - L[1], dz = L[5] - L[2];
    const float len = sqrtf(dx * dx + dy * dy + dz * dz);
    out[obase + (int)i] = s * vsw * len / fabsf(dz);
}

// ---------------------------------------------------------------------------
// Counting sort. Key: entry + exit transverse position, 8x8 x 8x8 = 4096
// bins. Position at slice k is a convex combination of the endpoints, so
// same-bin lanes stay within ~15-30 voxels of each other at EVERY k (the
// old midpoint+slope key let lanes drift up to ~90 voxels apart at extreme
// k, since slope was the minor key).
// ---------------------------------------------------------------------------
__device__ __forceinline__ int lor_key(const float* __restrict__ L)
{
    const int qa = min(7, max(0, (int)((L[0] + 60.0f) * 0.066666667f)));
    const int qb = min(7, max(0, (int)((L[1] + 60.0f) * 0.066666667f)));
    const int qc = min(7, max(0, (int)((L[3] + 60.0f) * 0.066666667f)));
    const int qd = min(7, max(0, (int)((L[4] + 60.0f) * 0.066666667f)));
    return (qa << 9) | (qb << 6) | (qc << 3) | qd;
}

__global__ __launch_bounds__(256)
void zero_bins(unsigned* __restrict__ bins, int n)
{
    const int t = blockIdx.x * 256 + threadIdx.x;
    if (t < n) bins[t] = 0u;
}

__global__ __launch_bounds__(256)
void hist_kernel(const float* __restrict__ xlp, const float* __restrict__ ylp,
                 const float* __restrict__ zlp,
                 int nx, int ny, int nz, unsigned* __restrict__ hist)
{
    const int t = blockIdx.x * 256 + threadIdx.x;
    const float* L; int set;
    if (t < nx)                { L = xlp + 6 * (size_t)t;              set = 0; }
    else if (t < nx + ny)      { L = ylp + 6 * (size_t)(t - nx);       set = 1; }
    else if (t < nx + ny + nz) { L = zlp + 6 * (size_t)(t - nx - ny);  set = 2; }
    else return;
    atomicAdd(&hist[set * NBIN_SET + lor_key(L)], 1u);
}

// Exclusive scan of each set's 4096 bins. One 1024-thread block per set.
__global__ __launch_bounds__(1024)
void scan_bins(const unsigned* __restrict__ hist, unsigned* __restrict__ offs)
{
    __shared__ unsigned part[1024];
    const int set = blockIdx.x;
    const unsigned* h = hist + set * NBIN_SET;
    unsigned* o = offs + set * NBIN_SET;
    const int t = threadIdx.x;

    unsigned loc[4];
    unsigned run = 0;
#pragma unroll
    for (int k = 0; k < 4; ++k) { loc[k] = run; run += h[t * 4 + k]; }
    part[t] = run;
    __syncthreads();
    for (int off = 1; off < 1024; off <<= 1) {
        const unsigned v = (t >= off) ? part[t - off] : 0u;
        __syncthreads();
        part[t] += v;
        __syncthreads();
    }
    const unsigned base = (t == 0) ? 0u : part[t - 1];
#pragma unroll
    for (int k = 0; k < 4; ++k) o[t * 4 + k] = base + loc[k];
}

__global__ __launch_bounds__(256)
void scatter_kernel(const float* __restrict__ xlp, const float* __restrict__ ylp,
                    const float* __restrict__ zlp,
                    int nx, int ny, int nz,
                    unsigned* __restrict__ offs, unsigned* __restrict__ perm)
{
    const int t = blockIdx.x * 256 + threadIdx.x;
    const float* L; int set, i, base;
    if (t < nx)                { L = xlp + 6 * (size_t)t;             set = 0; i = t;            base = 0;       }
    else if (t < nx + ny)      { L = ylp + 6 * (size_t)(t - nx);      set = 1; i = t - nx;       base = nx;      }
    else if (t < nx + ny + nz) { L = zlp + 6 * (size_t)(t - nx - ny); set = 2; i = t - nx - ny;  base = nx + ny; }
    else return;
    const unsigned pos = atomicAdd(&offs[set * NBIN_SET + lor_key(L)], 1u);
    perm[base + pos] = (unsigned)i;
}

// ---------------------------------------------------------------------------
// Middle-tier fallback (cooperative gather path): 32 lanes per LOR.
// ---------------------------------------------------------------------------
__device__ __forceinline__
float tor_chunk(const float* __restrict__ img,
                float fx0, float fy0, float dfx, float dfy,
                int k0, int n0, int n1, int s0, int s1)
{
    float fx[4], fy[4];
#pragma unroll
    for (int j = 0; j < 4; ++j) {
        fx[j] = fmaf((float)(k0 + j), dfx, fx0);
        fy[j] = fmaf((float)(k0 + j), dfy, fy0);
    }
    const float fxmin = fminf(fx[0], fx[3]), fxmax = fmaxf(fx[0], fx[3]);
    const float fymin = fminf(fy[0], fy[3]), fymax = fmaxf(fy[0], fy[3]);
    const int xlo = max(0,      (int)ceilf (fxmin - RW_F));
    const int xhi = min(n0 - 1, (int)floorf(fxmax + RW_F));

    float acc0 = 0.0f, acc1 = 0.0f, acc2 = 0.0f, acc3 = 0.0f;
    const float* rowp = img + xlo * s0 + k0;
    for (int jx = xlo; jx <= xhi; ++jx, rowp += s0) {
        float ddx2[4];
#pragma unroll
        for (int j = 0; j < 4; ++j) {
            const float dxx = (float)jx - fx[j];
            ddx2[j] = dxx * dxx;
        }
        const float rowmin =
            fminf(fminf(ddx2[0], ddx2[1]), fminf(ddx2[2], ddx2[3]));
        const float rad = fast_sqrtf(fmaxf(KW2_F - rowmin, 0.0f));
        const int ylo = max(0,      (int)ceilf (fymin - rad));
        const int yhi = min(n1 - 1, (int)floorf(fymax + rad));

        const float* p = rowp + ylo * s1;
        for (int jy = ylo; jy <= yhi; ++jy, p += s1) {
            const float4 v = *reinterpret_cast<const float4*>(p);
            float wg[4];
#pragma unroll
            for (int j = 0; j < 4; ++j) {
                const float dyy = (float)jy - fy[j];
                const float d2  = fmaf(dyy, dyy, ddx2[j]);
                wg[j] = fmaxf(0.0f, fmaf(-fast_sqrtf(d2), KW_INV, 1.0f));
            }
            acc0 = fmaf(wg[0], v.x, acc0);
            acc1 = fmaf(wg[1], v.y, acc1);
            acc2 = fmaf(wg[2], v.z, acc2);
            acc3 = fmaf(wg[3], v.w, acc3);
        }
    }
    return (acc0 + acc1) + (acc2 + acc3);
}

__global__ __launch_bounds__(256)
void proj_coop(const float* __restrict__ imgZ,
               const float* __restrict__ imgX,
               const float* __restrict__ xlp,
               const float* __restrict__ ylp,
               const float* __restrict__ zlp,
               const float* __restrict__ center,
               const float* __restrict__ size_,
               const unsigned* __restrict__ perm,
               float* __restrict__ out,
               int nx, int ny, int nz,
               int nbx, int nby, int G)
{
    const int b = blockIdx.x;
    const int G2 = G * G;
    const int sub  = threadIdx.x >> 5;
    const int lane = threadIdx.x & 31;

    const float* img; const float* lors; float* op;
    int a0, a1, a2, s0, s1;

    if (b < nbx) {
        const int idx = b * 8 + sub; if (idx >= nx) return;
        const int i = (int)perm[idx];
        img = imgX; lors = xlp + 6 * (size_t)i;  op = out + i;
        a0 = 2; a1 = 0; a2 = 1;  s0 = G2; s1 = G;
    } else if (b < nbx + nby) {
        const int idx = (b - nbx) * 8 + sub; if (idx >= ny) return;
        const int i = (int)perm[nx + idx];
        img = imgZ; lors = ylp + 6 * (size_t)i;  op = out + nx + i;
        a0 = 1; a1 = 0; a2 = 2;  s0 = G; s1 = G2;
    } else {
        const int idx = (b - nbx - nby) * 8 + sub; if (idx >= nz) return;
        const int i = (int)perm[nx + ny + idx];
        img = imgZ; lors = zlp + 6 * (size_t)i;  op = out + nx + ny + i;
        a0 = 0; a1 = 1; a2 = 2;  s0 = G2; s1 = G;
    }

    const float S0 = size_[a0], S1 = size_[a1], S2 = size_[a2];
    const float vs0 = S0 / (float)G, vs1 = S1 / (float)G, vs2 = S2 / (float)G;
    const float lo0 = center[a0] - 0.5f * S0;
    const float lo1 = center[a1] - 0.5f * S1;
    const float lo2 = center[a2] - 0.5f * S2;
    const float inv_vs0 = 1.0f / vs0, inv_vs1 = 1.0f / vs1;

    const float p1x = lors[0], p1y = lors[1], p1z = lors[2];
    const float p2x = lors[3], p2y = lors[4], p2z = lors[5];
    const float dx = p2x - p1x, dy = p2y - p1y, dz = p2z - p1z;
    const float len = sqrtf(dx * dx + dy * dy + dz * dz);
    const float inv_dz = 1.0f / dz;
    const float step = vs2 * len * fabsf(inv_dz);

    const float t0  = (lo2 + 0.5f * vs2 - p1z) * inv_dz;
    const float dt  = vs2 * inv_dz;
    const float fx0 = (fmaf(t0, dx, p1x) - lo0) * inv_vs0 - 0.5f;
    const float fy0 = (fmaf(t0, dy, p1y) - lo1) * inv_vs1 - 0.5f;
    const float dfx = dt * dx * inv_vs0;
    const float dfy = dt * dy * inv_vs1;

    float partialv = 0.0f;
    const int nchunks = G >> 2;
    for (int c = lane; c < nchunks; c += 32)
        partialv += tor_chunk(img, fx0, fy0, dfx, dfy, 4 * c, G, G, s0, s1);

#pragma unroll
    for (int m = 16; m >= 1; m >>= 1)
        partialv += __shfl_xor(partialv, m);

    if (lane == 0) *op = partialv * step;
}

// Scalar fallback (any G), one thread per LOR.
__device__ __forceinline__
float tor_lor_s(const float* __restrict__ img,
                const float* __restrict__ L,
                float lo0, float lo1, float lo2,
                float vs0, float vs1, float vs2,
                int n0, int n1, int n2, int s0, int s1, int s2)
{
    const float inv_vs0 = 1.0f / vs0, inv_vs1 = 1.0f / vs1;
    const float p1x = L[0], p1y = L[1], p1z = L[2];
    const float p2x = L[3], p2y = L[4], p2z = L[5];
    const float dx = p2x - p1x, dy = p2y - p1y, dz = p2z - p1z;
    const float len = sqrtf(dx * dx + dy * dy + dz * dz);
    const float inv_dz = 1.0f / dz;
    const float step = vs2 * len * fabsf(inv_dz);

    float acc_total = 0.0f;
    for (int k = 0; k < n2; ++k) {
        const float zc = lo2 + ((float)k + 0.5f) * vs2;
        const float t  = (zc - p1z) * inv_dz;
        const float fx = (fmaf(t, dx, p1x) - lo0) * inv_vs0 - 0.5f;
        const float fy = (fmaf(t, dy, p1y) - lo1) * inv_vs1 - 0.5f;
        const int ix = (int)rintf(fx);
        const int iy = (int)rintf(fy);
        const int kb = k * s2;
        float acc = 0.0f;
#pragma unroll
        for (int o0 = -2; o0 <= 2; ++o0) {
            const int jx = ix + o0;
            if ((unsigned)jx >= (unsigned)n0) continue;
            const float dxx  = (float)jx - fx;
            const float ddx2 = dxx * dxx;
            if (ddx2 >= KW2_F) continue;
            const int xb = jx * s0 + kb;
#pragma unroll
            for (int o1 = -2; o1 <= 2; ++o1) {
                const int jy = iy + o1;
                if ((unsigned)jy >= (unsigned)n1) continue;
                const float dyy = (float)jy - fy;
                const float d2  = fmaf(dyy, dyy, ddx2);
                if (d2 < KW2_F) {
                    const float w = fmaf(-fast_sqrtf(d2), KW_INV, 1.0f);
                    acc = fmaf(w, img[xb + jy * s1], acc);
                }
            }
        }
        acc_total += acc;
    }
    return acc_total * step;
}

__global__ __launch_bounds__(256)
void proj_fallback(const float* __restrict__ img,
                   const float* __restrict__ xlp,
                   const float* __restrict__ ylp,
                   const float* __restrict__ zlp,
                   const float* __restrict__ center,
                   const float* __restrict__ size_,
                   float* __restrict__ out,
                   int nx, int ny, int nz,
                   int nbx, int nby, int G)
{
    const int b = blockIdx.x;
    const int G2 = G * G;
    const float* lors; float* op;
    int a0, a1, a2, s0, s1, s2;

    if (b < nbx) {
        const int i = b * 256 + threadIdx.x; if (i >= nx) return;
        lors = xlp + 6 * (size_t)i;  op = out + i;
        a0 = 2; a1 = 0; a2 = 1;  s0 = 1; s1 = G2; s2 = G;
    } else if (b < nbx + nby) {
        const int i = (b - nbx) * 256 + threadIdx.x; if (i >= ny) return;
        lors = ylp + 6 * (size_t)i;  op = out + nx + i;
        a0 = 1; a1 = 0; a2 = 2;  s0 = G; s1 = G2; s2 = 1;
    } else {
        const int i = (b - nbx - nby) * 256 + threadIdx.x; if (i >= nz) return;
        lors = zlp + 6 * (size_t)i;  op = out + nx + ny + i;
        a0 = 0; a1 = 1; a2 = 2;  s0 = G2; s1 = G; s2 = 1;
    }

    const float S0 = size_[a0], S1 = size_[a1], S2 = size_[a2];
    const float vs0 = S0 / (float)G, vs1 = S1 / (float)G, vs2 = S2 / (float)G;
    *op = tor_lor_s(img, lors,
                    center[a0] - 0.5f * S0, center[a1] - 0.5f * S1,
                    center[a2] - 0.5f * S2,
                    vs0, vs1, vs2, G, G, G, s0, s1, s2);
}

// 2D transpose in[R][C] -> out[C][R]; Px[a,i0,i1] = image[i0,i1,a].
__global__ __launch_bounds__(256)
void transpose_RC(const float* __restrict__ in, float* __restrict__ outp,
                  int R, int C)
{
    __shared__ float tile[32][33];
    const int rt = blockIdx.x * 32;
    const int ct = blockIdx.y * 32;
    const int tx = threadIdx.x;
    const int ty = threadIdx.y;   // block (32,8)
#pragma unroll
    for (int j = 0; j < 32; j += 8)
        tile[ty + j][tx] = in[(size_t)(rt + ty + j) * C + (ct + tx)];
    __syncthreads();
#pragma unroll
    for (int j = 0; j < 32; j += 8)
        outp[(size_t)(ct + ty + j) * R + (rt + tx)] = tile[tx][ty + j];
}

extern "C" void kernel_launch(void* const* d_in, const int* in_sizes, int n_in,
                              void* d_out, int out_size, void* d_ws, size_t ws_size,
                              hipStream_t stream)
{
    const float* img    = (const float*)d_in[0];
    const float* center = (const float*)d_in[2];
    const float* size_  = (const float*)d_in[3];
    const float* xlors  = (const float*)d_in[4];
    const float* ylors  = (const float*)d_in[5];
    const float* zlors  = (const float*)d_in[6];
    float* out = (float*)d_out;

    const int nx = in_sizes[4] / 6;
    const int ny = in_sizes[5] / 6;
    const int nz = in_sizes[6] / 6;
    const int ntot = nx + ny + nz;

    int G = (int)lround(cbrt((double)in_sizes[0]));
    const int G2 = G * G;

    // Workspace: [Px G^3 f32][hist 3*4096][offs 3*4096][perm ntot][partial KGC*ntot]
    const size_t pxBytes  = (size_t)G * G2 * sizeof(float);
    const int    nbins    = 3 * NBIN_SET;
    const size_t sortB    = 2 * (size_t)nbins * sizeof(unsigned)
                          + (size_t)ntot * sizeof(unsigned);
    const size_t needSlab = pxBytes + sortB + (size_t)KGC * ntot * sizeof(float);
    const size_t needCoop = pxBytes + sortB;

    const bool slab = (G == 128) && (ws_size >= needSlab);
    const bool coop = !slab && (G % 32 == 0) && (ws_size >= needCoop);

    if (slab || coop) {
        float*    Px   = (float*)d_ws;
        unsigned* hist = (unsigned*)((char*)d_ws + pxBytes);
        unsigned* offs = hist + nbins;
        unsigned* perm = offs + nbins;
        float*    part = (float*)(perm + ntot);

        transpose_RC<<<dim3(G2 / 32, G / 32), dim3(32, 8), 0, stream>>>(
            img, Px, G2, G);

        zero_bins<<<(nbins + 255) / 256, 256, 0, stream>>>(hist, nbins);
        hist_kernel<<<(ntot + 255) / 256, 256, 0, stream>>>(
            xlors, ylors, zlors, nx, ny, nz, hist);
        scan_bins<<<3, 1024, 0, stream>>>(hist, offs);
        scatter_kernel<<<(ntot + 255) / 256, 256, 0, stream>>>(
            xlors, ylors, zlors, nx, ny, nz, offs, perm);

        if (slab) {
            const int cap = TPB * MAXL;
            const int Sx = max(1, (nx + cap - 1) / cap);
            const int Sb = max(1, (ny + nz + cap - 1) / cap);
            proj_slab<<<KGC * (Sx + Sb), TPB, 0, stream>>>(
                img, Px, xlors, ylors, zlors, center, size_, perm, part,
                nx, ny, nz, Sx, Sb);
            finalize_kernel<<<(ntot + 255) / 256, 256, 0, stream>>>(
                xlors, ylors, zlors, size_, perm, part, out, nx, ny, nz, G);
        } else {
            const int nbx = (nx + 7) / 8;
            const int nby = (ny + 7) / 8;
            const int nbz = (nz + 7) / 8;
            proj_coop<<<nbx + nby + nbz, 256, 0, stream>>>(
                img, Px, xlors, ylors, zlors, center, size_, perm, out,
                nx, ny, nz, nbx, nby, G);
        }
    } else {
        const int nbx = (nx + 255) / 256;
        const int nby = (ny + 255) / 256;
        const int nbz = (nz + 255) / 256;
        proj_fallback<<<nbx + nby + nbz, 256, 0, stream>>>(
            img, xlors, ylors, zlors, center, size_, out,
            nx, ny, nz, nbx, nby, G);
    }
}

// Round 16
// 455.018 us; speedup vs baseline: 1.4854x; 1.0607x over previous
//
#include <hip/hip_runtime.h>
#include <math.h>

// KERNEL_WIDTH = sqrt(9/pi) = 1.6925687506432297
#define KW2_F  2.8647889756541161f   // (9/pi)
#define KW_INV 0.5908179502964271f   // 1/KW
#define RW_F   1.6926f               // slightly >= KW (safe superset bound)

#define NBIN_SET 4096   // entry 8x8 x exit 8x8 transverse bins, per LOR set
#define TPB      1024   // slab-kernel block size (2 blocks/CU -> 32 waves/CU)
#define MAXL     4      // LORs per thread (cap 4096/block -> grid packs 3x512)
#define KG       16     // k-slices per block
#define KGC      8      // 128 / KG
#define TROW     132    // 128+4: float4-aligned staging; measured best conflicts

typedef __attribute__((ext_vector_type(2))) float f2;

__device__ __forceinline__ float fast_sqrtf(float x) {
    return __builtin_amdgcn_sqrtf(x);   // raw v_sqrt_f32, ~1 ulp
}

// weight pair: w = max(0, 1 - sqrt(d2)/KW), elementwise on 2 taps
__device__ __forceinline__ f2 wpair(f2 d2) {
    f2 s;
    s.x = fast_sqrtf(d2.x);
    s.y = fast_sqrtf(d2.y);
    f2 w = 1.0f - s * KW_INV;
    w.x = fmaxf(w.x, 0.0f);
    w.y = fmaxf(w.y, 0.0f);
    return w;
}

// ---------------------------------------------------------------------------
// Slab projection kernel. G == 128 only (gated on host).
//
// Geometry:
//   x-set: walks orig axis1; u = orig0 (L[1],L[4]), v = orig2 (L[0],L[3]).
//          Slab = image[:, k, :] (rows of 512 B, coalesced).
//   y-set: walks orig axis2; u = orig0 (L[1],L[4]), v = orig1 (L[0],L[3]).
//   z-set: walks orig axis2; u = orig0 (L[0],L[3]), v = orig1 (L[1],L[4]).
//          y/z slab = Px[k] plane (contiguous 64 KB).
//
// Inner loop: FIXED 4x4 window at (ceil(u-RW), ceil(v-RW)); w>0 disk diameter
// 2*KW = 3.385 < 4 -> covers every reference tap with w>0; w clamps at 0 for
// the rest -> identical sum. Tap (3,3) is provably w==0 (du3^2 >= 1.709,
// dv3^2 >= 1.709, sum 3.42 > 9/pi) and is skipped -> 15 taps.
// Output: per-k-group partial sums to a [KGC][ntot] buffer (coalesced),
// reduced by finalize_kernel (deterministic).
// Grid is sized on the host to a multiple of 512 resident block slots
// (2 blocks/CU x 256 CU) for full scheduling-round packing.
// ---------------------------------------------------------------------------
__global__ __launch_bounds__(TPB, 2)
void proj_slab(const float* __restrict__ img,
               const float* __restrict__ Px,
               const float* __restrict__ xl,
               const float* __restrict__ yl,
               const float* __restrict__ zl,
               const float* __restrict__ center,
               const float* __restrict__ size_,
               const unsigned* __restrict__ perm,
               float* __restrict__ partial,
               int nx, int ny, int nz, int Sx, int Sb)
{
    const int G = 128, G2 = 128 * 128;
    __shared__ float tile[128 * TROW];   // 67.6 KB -> 2 blocks/CU

    const int b   = blockIdx.x;
    const int tid = threadIdx.x;
    const int nB  = ny + nz;
    const int ntot = nx + nB;

    int kg, lo, hi, isA;
    if (b < KGC * Sx) {
        isA = 1; kg = b / Sx;
        const int sp = b % Sx;
        const int c  = (nx + Sx - 1) / Sx;
        lo = sp * c; hi = min(nx, lo + c);
    } else {
        isA = 0;
        const int bb = b - KGC * Sx;
        kg = bb / Sb;
        const int sp = bb % Sb;
        const int c  = (nB + Sb - 1) / Sb;
        lo = sp * c; hi = min(nB, lo + c);
    }
    const int k0 = kg * KG;

    // block-uniform geometry (au = 0 for all sets)
    const int av = isA ? 2 : 1;
    const int aw = isA ? 1 : 2;
    const float vsu = size_[0] / (float)G, inv_vsu = 1.0f / vsu;
    const float vsv = size_[av] / (float)G, inv_vsv = 1.0f / vsv;
    const float vsw = size_[aw] / (float)G;
    const float luo = center[0]  - 0.5f * size_[0];
    const float lvo = center[av] - 0.5f * size_[av];
    const float wlo = center[aw] - 0.5f * size_[aw];

    float fu0[MAXL], fv0[MAXL], duk[MAXL], dvk[MAXL], acc[MAXL];

#pragma unroll
    for (int l = 0; l < MAXL; ++l) {
        const int idx = lo + tid + l * TPB;
        acc[l] = 0.0f;
        if (idx < hi) {
            const float* L;
            float pu1, pu2, pv1, pv2;
            if (isA) {
                const unsigned i = perm[idx];
                L = xl + 6 * (size_t)i;
                pu1 = L[1]; pu2 = L[4]; pv1 = L[0]; pv2 = L[3];
            } else if (idx < ny) {
                const unsigned i = perm[nx + idx];
                L = yl + 6 * (size_t)i;
                pu1 = L[1]; pu2 = L[4]; pv1 = L[0]; pv2 = L[3];
            } else {
                const unsigned i = perm[nx + idx];
                L = zl + 6 * (size_t)i;
                pu1 = L[0]; pu2 = L[3]; pv1 = L[1]; pv2 = L[4];
            }
            const float pw1 = L[2], pw2 = L[5];
            const float inv_dw = 1.0f / (pw2 - pw1);
            const float dt = vsw * inv_dw;
            const float t0 = (wlo + 0.5f * vsw - pw1) * inv_dw;
            const float dU = pu2 - pu1, dV = pv2 - pv1;
            fu0[l] = (fmaf(t0, dU, pu1) - luo) * inv_vsu - 0.5f;
            fv0[l] = (fmaf(t0, dV, pv1) - lvo) * inv_vsv - 0.5f;
            duk[l] = dt * dU * inv_vsu;
            dvk[l] = dt * dV * inv_vsv;
        } else {
            fu0[l] = -1e9f; fv0[l] = -1e9f; duk[l] = 0.0f; dvk[l] = 0.0f;
        }
    }

    for (int kk = k0; kk < k0 + KG; ++kk) {
        __syncthreads();   // previous iteration's reads done before overwrite
        if (isA) {
#pragma unroll
            for (int it = 0; it < 4; ++it) {
                const int f = (tid + it * TPB) * 4;   // float index in plane
                const int r = f >> 7, c = f & 127;
                const float4 v = *reinterpret_cast<const float4*>(
                    img + (size_t)r * G2 + kk * G + c);
                *reinterpret_cast<float4*>(tile + r * TROW + c) = v;
            }
        } else {
#pragma unroll
            for (int it = 0; it < 4; ++it) {
                const int f = (tid + it * TPB) * 4;
                const int r = f >> 7, c = f & 127;
                const float4 v = *reinterpret_cast<const float4*>(
                    Px + (size_t)kk * G2 + f);
                *reinterpret_cast<float4*>(tile + r * TROW + c) = v;
            }
        }
        __syncthreads();

        const float fk = (float)kk;
#pragma unroll
        for (int l = 0; l < MAXL; ++l) {
            const float u = fmaf(fk, duk[l], fu0[l]);
            const float v = fmaf(fk, dvk[l], fv0[l]);
            const float fulo = ceilf(u - RW_F);
            const float fvlo = ceilf(v - RW_F);
            const int ulo = (int)fulo;
            const int vlo = (int)fvlo;
            float a = acc[l];
            if ((unsigned)ulo <= 124u && (unsigned)vlo <= 124u) {
                // interior fast path: straight-line 15 taps, uniform lanes
                const float du0 = fulo - u, dv0 = fvlo - v;
                float du2[4], dv2[4];
#pragma unroll
                for (int r = 0; r < 4; ++r) {
                    const float dr = du0 + (float)r; du2[r] = dr * dr;
                    const float dc = dv0 + (float)r; dv2[r] = dc * dc;
                }
                const float* tp = tile + (ulo * TROW + vlo);
                f2 accp = {0.0f, 0.0f};
#pragma unroll
                for (int r = 0; r < 3; ++r) {
                    const f2 d2a = {du2[r] + dv2[0], du2[r] + dv2[1]};
                    const f2 d2b = {du2[r] + dv2[2], du2[r] + dv2[3]};
                    const f2 wa = wpair(d2a);
                    const f2 wb = wpair(d2b);
                    const f2 va = {tp[r * TROW + 0], tp[r * TROW + 1]};
                    const f2 vb = {tp[r * TROW + 2], tp[r * TROW + 3]};
                    accp += wa * va;
                    accp += wb * vb;
                }
                {   // row 3: taps (3,0),(3,1),(3,2); (3,3) provably w==0
                    const f2 d2a = {du2[3] + dv2[0], du2[3] + dv2[1]};
                    const f2 wa = wpair(d2a);
                    const f2 va = {tp[3 * TROW + 0], tp[3 * TROW + 1]};
                    accp += wa * va;
                    const float d2c = du2[3] + dv2[2];
                    const float wc =
                        fmaxf(0.0f, fmaf(-fast_sqrtf(d2c), KW_INV, 1.0f));
                    a = fmaf(wc, tp[3 * TROW + 2], a);
                }
                acc[l] = a + accp.x + accp.y;
            } else if (u > -RW_F && u < 127.0f + RW_F &&
                       v > -RW_F && v < 127.0f + RW_F) {
                // edge path: masked taps (rare)
#pragma unroll
                for (int r = 0; r < 4; ++r) {
                    const int ju = ulo + r;
                    const float dd = (float)ju - u;
                    const float dd2 = dd * dd;
                    const int rb = min(max(ju, 0), 127) * TROW;
                    const bool rok = (unsigned)ju < 128u;
#pragma unroll
                    for (int c = 0; c < 4; ++c) {
                        const int jv = vlo + c;
                        const float dvv = (float)jv - v;
                        const float d2 = fmaf(dvv, dvv, dd2);
                        float w =
                            fmaxf(0.0f, fmaf(-fast_sqrtf(d2), KW_INV, 1.0f));
                        if (!(rok && (unsigned)jv < 128u)) w = 0.0f;
                        a = fmaf(w, tile[rb + min(max(jv, 0), 127)], a);
                    }
                }
                acc[l] = a;
            }
        }
    }

#pragma unroll
    for (int l = 0; l < MAXL; ++l) {
        const int idx = lo + tid + l * TPB;
        if (idx < hi) {
            const int sidx = isA ? idx : nx + idx;
            partial[(size_t)kg * ntot + sidx] = acc[l];
        }
    }
}

// Finalize: sum KGC partials, apply step, un-permute.
__global__ __launch_bounds__(256)
void finalize_kernel(const float* __restrict__ xl,
                     const float* __restrict__ yl,
                     const float* __restrict__ zl,
                     const float* __restrict__ size_,
                     const unsigned* __restrict__ perm,
                     const float* __restrict__ partial,
                     float* __restrict__ out,
                     int nx, int ny, int nz, int G)
{
    const int t = blockIdx.x * 256 + threadIdx.x;
    const int ntot = nx + ny + nz;
    if (t >= ntot) return;

    const unsigned i = perm[t];
    const float* L; int obase; float vsw;
    if (t < nx)           { L = xl + 6 * (size_t)i; obase = 0;       vsw = size_[1] / (float)G; }
    else if (t < nx + ny) { L = yl + 6 * (size_t)i; obase = nx;      vsw = size_[2] / (float)G; }
    else                  { L = zl + 6 * (size_t)i; obase = nx + ny; vsw = size_[2] / (float)G; }

    float s = 0.0f;
#pragma unroll
    for (int kg = 0; kg < KGC; ++kg) s += partial[(size_t)kg * ntot + t];

    const float dx = L[3] - L[0], dy = L[4] - L[1], dz = L[5] - L[2];
    const float len = sqrtf(dx * dx + dy * dy + dz * dz);
    out[obase + (int)i] = s * vsw * len / fabsf(dz);
}

// ---------------------------------------------------------------------------
// Counting sort. Key: entry + exit transverse position, 8x8 x 8x8 = 4096
// bins. Position at slice k is a convex combination of the endpoints, so
// same-bin lanes stay close at every k.
// ---------------------------------------------------------------------------
__device__ __forceinline__ int lor_key(const float* __restrict__ L)
{
    const int qa = min(7, max(0, (int)((L[0] + 60.0f) * 0.066666667f)));
    const int qb = min(7, max(0, (int)((L[1] + 60.0f) * 0.066666667f)));
    const int qc = min(7, max(0, (int)((L[3] + 60.0f) * 0.066666667f)));
    const int qd = min(7, max(0, (int)((L[4] + 60.0f) * 0.066666667f)));
    return (qa << 9) | (qb << 6) | (qc << 3) | qd;
}

__global__ __launch_bounds__(256)
void hist_kernel(const float* __restrict__ xlp, const float* __restrict__ ylp,
                 const float* __restrict__ zlp,
                 int nx, int ny, int nz, unsigned* __restrict__ hist)
{
    const int t = blockIdx.x * 256 + threadIdx.x;
    const float* L; int set;
    if (t < nx)                { L = xlp + 6 * (size_t)t;              set = 0; }
    else if (t < nx + ny)      { L = ylp + 6 * (size_t)(t - nx);       set = 1; }
    else if (t < nx + ny + nz) { L = zlp + 6 * (size_t)(t - nx - ny);  set = 2; }
    else return;
    atomicAdd(&hist[set * NBIN_SET + lor_key(L)], 1u);
}

// Exclusive scan of each set's 4096 bins. One 1024-thread block per set.
__global__ __launch_bounds__(1024)
void scan_bins(const unsigned* __restrict__ hist, unsigned* __restrict__ offs)
{
    __shared__ unsigned part[1024];
    const int set = blockIdx.x;
    const unsigned* h = hist + set * NBIN_SET;
    unsigned* o = offs + set * NBIN_SET;
    const int t = threadIdx.x;

    unsigned loc[4];
    unsigned run = 0;
#pragma unroll
    for (int k = 0; k < 4; ++k) { loc[k] = run; run += h[t * 4 + k]; }
    part[t] = run;
    __syncthreads();
    for (int off = 1; off < 1024; off <<= 1) {
        const unsigned v = (t >= off) ? part[t - off] : 0u;
        __syncthreads();
        part[t] += v;
        __syncthreads();
    }
    const unsigned base = (t == 0) ? 0u : part[t - 1];
#pragma unroll
    for (int k = 0; k < 4; ++k) o[t * 4 + k] = base + loc[k];
}

__global__ __launch_bounds__(256)
void scatter_kernel(const float* __restrict__ xlp, const float* __restrict__ ylp,
                    const float* __restrict__ zlp,
                    int nx, int ny, int nz,
                    unsigned* __restrict__ offs, unsigned* __restrict__ perm)
{
    const int t = blockIdx.x * 256 + threadIdx.x;
    const float* L; int set, i, base;
    if (t < nx)                { L = xlp + 6 * (size_t)t;             set = 0; i = t;            base = 0;       }
    else if (t < nx + ny)      { L = ylp + 6 * (size_t)(t - nx);      set = 1; i = t - nx;       base = nx;      }
    else if (t < nx + ny + nz) { L = zlp + 6 * (size_t)(t - nx - ny); set = 2; i = t - nx - ny;  base = nx + ny; }
    else return;
    const unsigned pos = atomicAdd(&offs[set * NBIN_SET + lor_key(L)], 1u);
    perm[base + pos] = (unsigned)i;
}

// ---------------------------------------------------------------------------
// Middle-tier fallback (cooperative gather path): 32 lanes per LOR.
// ---------------------------------------------------------------------------
__device__ __forceinline__
float tor_chunk(const float* __restrict__ img,
                float fx0, float fy0, float dfx, float dfy,
                int k0, int n0, int n1, int s0, int s1)
{
    float fx[4], fy[4];
#pragma unroll
    for (int j = 0; j < 4; ++j) {
        fx[j] = fmaf((float)(k0 + j), dfx, fx0);
        fy[j] = fmaf((float)(k0 + j), dfy, fy0);
    }
    const float fxmin = fminf(fx[0], fx[3]), fxmax = fmaxf(fx[0], fx[3]);
    const float fymin = fminf(fy[0], fy[3]), fymax = fmaxf(fy[0], fy[3]);
    const int xlo = max(0,      (int)ceilf (fxmin - RW_F));
    const int xhi = min(n0 - 1, (int)floorf(fxmax + RW_F));

    float acc0 = 0.0f, acc1 = 0.0f, acc2 = 0.0f, acc3 = 0.0f;
    const float* rowp = img + xlo * s0 + k0;
    for (int jx = xlo; jx <= xhi; ++jx, rowp += s0) {
        float ddx2[4];
#pragma unroll
        for (int j = 0; j < 4; ++j) {
            const float dxx = (float)jx - fx[j];
            ddx2[j] = dxx * dxx;
        }
        const float rowmin =
            fminf(fminf(ddx2[0], ddx2[1]), fminf(ddx2[2], ddx2[3]));
        const float rad = fast_sqrtf(fmaxf(KW2_F - rowmin, 0.0f));
        const int ylo = max(0,      (int)ceilf (fymin - rad));
        const int yhi = min(n1 - 1, (int)floorf(fymax + rad));

        const float* p = rowp + ylo * s1;
        for (int jy = ylo; jy <= yhi; ++jy, p += s1) {
            const float4 v = *reinterpret_cast<const float4*>(p);
            float wg[4];
#pragma unroll
            for (int j = 0; j < 4; ++j) {
                const float dyy = (float)jy - fy[j];
                const float d2  = fmaf(dyy, dyy, ddx2[j]);
                wg[j] = fmaxf(0.0f, fmaf(-fast_sqrtf(d2), KW_INV, 1.0f));
            }
            acc0 = fmaf(wg[0], v.x, acc0);
            acc1 = fmaf(wg[1], v.y, acc1);
            acc2 = fmaf(wg[2], v.z, acc2);
            acc3 = fmaf(wg[3], v.w, acc3);
        }
    }
    return (acc0 + acc1) + (acc2 + acc3);
}

__global__ __launch_bounds__(256)
void proj_coop(const float* __restrict__ imgZ,
               const float* __restrict__ imgX,
               const float* __restrict__ xlp,
               const float* __restrict__ ylp,
               const float* __restrict__ zlp,
               const float* __restrict__ center,
               const float* __restrict__ size_,
               const unsigned* __restrict__ perm,
               float* __restrict__ out,
               int nx, int ny, int nz,
               int nbx, int nby, int G)
{
    const int b = blockIdx.x;
    const int G2 = G * G;
    const int sub  = threadIdx.x >> 5;
    const int lane = threadIdx.x & 31;

    const float* img; const float* lors; float* op;
    int a0, a1, a2, s0, s1;

    if (b < nbx) {
        const int idx = b * 8 + sub; if (idx >= nx) return;
        const int i = (int)perm[idx];
        img = imgX; lors = xlp + 6 * (size_t)i;  op = out + i;
        a0 = 2; a1 = 0; a2 = 1;  s0 = G2; s1 = G;
    } else if (b < nbx + nby) {
        const int idx = (b - nbx) * 8 + sub; if (idx >= ny) return;
        const int i = (int)perm[nx + idx];
        img = imgZ; lors = ylp + 6 * (size_t)i;  op = out + nx + i;
        a0 = 1; a1 = 0; a2 = 2;  s0 = G; s1 = G2;
    } else {
        const int idx = (b - nbx - nby) * 8 + sub; if (idx >= nz) return;
        const int i = (int)perm[nx + ny + idx];
        img = imgZ; lors = zlp + 6 * (size_t)i;  op = out + nx + ny + i;
        a0 = 0; a1 = 1; a2 = 2;  s0 = G2; s1 = G;
    }

    const float S0 = size_[a0], S1 = size_[a1], S2 = size_[a2];
    const float vs0 = S0 / (float)G, vs1 = S1 / (float)G, vs2 = S2 / (float)G;
    const float lo0 = center[a0] - 0.5f * S0;
    const float lo1 = center[a1] - 0.5f * S1;
    const float lo2 = center[a2] - 0.5f * S2;
    const float inv_vs0 = 1.0f / vs0, inv_vs1 = 1.0f / vs1;

    const float p1x = lors[0], p1y = lors[1], p1z = lors[2];
    const float p2x = lors[3], p2y = lors[4], p2z = lors[5];
    const float dx = p2x - p1x, dy = p2y - p1y, dz = p2z - p1z;
    const float len = sqrtf(dx * dx + dy * dy + dz * dz);
    const float inv_dz = 1.0f / dz;
    const float step = vs2 * len * fabsf(inv_dz);

    const float t0  = (lo2 + 0.5f * vs2 - p1z) * inv_dz;
    const float dt  = vs2 * inv_dz;
    const float fx0 = (fmaf(t0, dx, p1x) - lo0) * inv_vs0 - 0.5f;
    const float fy0 = (fmaf(t0, dy, p1y) - lo1) * inv_vs1 - 0.5f;
    const float dfx = dt * dx * inv_vs0;
    const float dfy = dt * dy * inv_vs1;

    float partialv = 0.0f;
    const int nchunks = G >> 2;
    for (int c = lane; c < nchunks; c += 32)
        partialv += tor_chunk(img, fx0, fy0, dfx, dfy, 4 * c, G, G, s0, s1);

#pragma unroll
    for (int m = 16; m >= 1; m >>= 1)
        partialv += __shfl_xor(partialv, m);

    if (lane == 0) *op = partialv * step;
}

// Scalar fallback (any G), one thread per LOR.
__device__ __forceinline__
float tor_lor_s(const float* __restrict__ img,
                const float* __restrict__ L,
                float lo0, float lo1, float lo2,
                float vs0, float vs1, float vs2,
                int n0, int n1, int n2, int s0, int s1, int s2)
{
    const float inv_vs0 = 1.0f / vs0, inv_vs1 = 1.0f / vs1;
    const float p1x = L[0], p1y = L[1], p1z = L[2];
    const float p2x = L[3], p2y = L[4], p2z = L[5];
    const float dx = p2x - p1x, dy = p2y - p1y, dz = p2z - p1z;
    const float len = sqrtf(dx * dx + dy * dy + dz * dz);
    const float inv_dz = 1.0f / dz;
    const float step = vs2 * len * fabsf(inv_dz);

    float acc_total = 0.0f;
    for (int k = 0; k < n2; ++k) {
        const float zc = lo2 + ((float)k + 0.5f) * vs2;
        const float t  = (zc - p1z) * inv_dz;
        const float fx = (fmaf(t, dx, p1x) - lo0) * inv_vs0 - 0.5f;
        const float fy = (fmaf(t, dy, p1y) - lo1) * inv_vs1 - 0.5f;
        const int ix = (int)rintf(fx);
        const int iy = (int)rintf(fy);
        const int kb = k * s2;
        float acc = 0.0f;
#pragma unroll
        for (int o0 = -2; o0 <= 2; ++o0) {
            const int jx = ix + o0;
            if ((unsigned)jx >= (unsigned)n0) continue;
            const float dxx  = (float)jx - fx;
            const float ddx2 = dxx * dxx;
            if (ddx2 >= KW2_F) continue;
            const int xb = jx * s0 + kb;
#pragma unroll
            for (int o1 = -2; o1 <= 2; ++o1) {
                const int jy = iy + o1;
                if ((unsigned)jy >= (unsigned)n1) continue;
                const float dyy = (float)jy - fy;
                const float d2  = fmaf(dyy, dyy, ddx2);
                if (d2 < KW2_F) {
                    const float w = fmaf(-fast_sqrtf(d2), KW_INV, 1.0f);
                    acc = fmaf(w, img[xb + jy * s1], acc);
                }
            }
        }
        acc_total += acc;
    }
    return acc_total * step;
}

__global__ __launch_bounds__(256)
void proj_fallback(const float* __restrict__ img,
                   const float* __restrict__ xlp,
                   const float* __restrict__ ylp,
                   const float* __restrict__ zlp,
                   const float* __restrict__ center,
                   const float* __restrict__ size_,
                   float* __restrict__ out,
                   int nx, int ny, int nz,
                   int nbx, int nby, int G)
{
    const int b = blockIdx.x;
    const int G2 = G * G;
    const float* lors; float* op;
    int a0, a1, a2, s0, s1, s2;

    if (b < nbx) {
        const int i = b * 256 + threadIdx.x; if (i >= nx) return;
        lors = xlp + 6 * (size_t)i;  op = out + i;
        a0 = 2; a1 = 0; a2 = 1;  s0 = 1; s1 = G2; s2 = G;
    } else if (b < nbx + nby) {
        const int i = (b - nbx) * 256 + threadIdx.x; if (i >= ny) return;
        lors = ylp + 6 * (size_t)i;  op = out + nx + i;
        a0 = 1; a1 = 0; a2 = 2;  s0 = G; s1 = G2; s2 = 1;
    } else {
        const int i = (b - nbx - nby) * 256 + threadIdx.x; if (i >= nz) return;
        lors = zlp + 6 * (size_t)i;  op = out + nx + ny + i;
        a0 = 0; a1 = 1; a2 = 2;  s0 = G2; s1 = G; s2 = 1;
    }

    const float S0 = size_[a0], S1 = size_[a1], S2 = size_[a2];
    const float vs0 = S0 / (float)G, vs1 = S1 / (float)G, vs2 = S2 / (float)G;
    *op = tor_lor_s(img, lors,
                    center[a0] - 0.5f * S0, center[a1] - 0.5f * S1,
                    center[a2] - 0.5f * S2,
                    vs0, vs1, vs2, G, G, G, s0, s1, s2);
}

// 2D transpose in[R][C] -> out[C][R]; Px[a,i0,i1] = image[i0,i1,a].
__global__ __launch_bounds__(256)
void transpose_RC(const float* __restrict__ in, float* __restrict__ outp,
                  int R, int C)
{
    __shared__ float tile[32][33];
    const int rt = blockIdx.x * 32;
    const int ct = blockIdx.y * 32;
    const int tx = threadIdx.x;
    const int ty = threadIdx.y;   // block (32,8)
#pragma unroll
    for (int j = 0; j < 32; j += 8)
        tile[ty + j][tx] = in[(size_t)(rt + ty + j) * C + (ct + tx)];
    __syncthreads();
#pragma unroll
    for (int j = 0; j < 32; j += 8)
        outp[(size_t)(ct + ty + j) * R + (rt + tx)] = tile[tx][ty + j];
}

extern "C" void kernel_launch(void* const* d_in, const int* in_sizes, int n_in,
                              void* d_out, int out_size, void* d_ws, size_t ws_size,
                              hipStream_t stream)
{
    const float* img    = (const float*)d_in[0];
    const float* center = (const float*)d_in[2];
    const float* size_  = (const float*)d_in[3];
    const float* xlors  = (const float*)d_in[4];
    const float* ylors  = (const float*)d_in[5];
    const float* zlors  = (const float*)d_in[6];
    float* out = (float*)d_out;

    const int nx = in_sizes[4] / 6;
    const int ny = in_sizes[5] / 6;
    const int nz = in_sizes[6] / 6;
    const int nB   = ny + nz;
    const int ntot = nx + nB;

    int G = (int)lround(cbrt((double)in_sizes[0]));
    const int G2 = G * G;

    // Workspace: [Px G^3 f32][hist 3*4096][offs 3*4096][perm ntot][partial KGC*ntot]
    const size_t pxBytes  = (size_t)G * G2 * sizeof(float);
    const int    nbins    = 3 * NBIN_SET;
    const size_t sortB    = 2 * (size_t)nbins * sizeof(unsigned)
                          + (size_t)ntot * sizeof(unsigned);
    const size_t needSlab = pxBytes + sortB + (size_t)KGC * ntot * sizeof(float);
    const size_t needCoop = pxBytes + sortB;

    const bool slab = (G == 128) && (ws_size >= needSlab);
    const bool coop = !slab && (G % 32 == 0) && (ws_size >= needCoop);

    if (slab || coop) {
        float*    Px   = (float*)d_ws;
        unsigned* hist = (unsigned*)((char*)d_ws + pxBytes);
        unsigned* offs = hist + nbins;
        unsigned* perm = offs + nbins;
        float*    part = (float*)(perm + ntot);

        transpose_RC<<<dim3(G2 / 32, G / 32), dim3(32, 8), 0, stream>>>(
            img, Px, G2, G);

        hipMemsetAsync(hist, 0, (size_t)nbins * sizeof(unsigned), stream);
        hist_kernel<<<(ntot + 255) / 256, 256, 0, stream>>>(
            xlors, ylors, zlors, nx, ny, nz, hist);
        scan_bins<<<3, 1024, 0, stream>>>(hist, offs);
        scatter_kernel<<<(ntot + 255) / 256, 256, 0, stream>>>(
            xlors, ylors, zlors, nx, ny, nz, offs, perm);

        if (slab) {
            // Pack the grid into full scheduling rounds: 2 blocks/CU x 256 CU
            // = 512 resident slots; make KGC*(Sx+Sb) a multiple of 512, i.e.
            // Sx+Sb a multiple of 64, with uniform chunks <= TPB*MAXL.
            const int cap = TPB * MAXL;
            int Sx0 = max(1, (nx + cap - 1) / cap);
            int Sb0 = max(1, (nB + cap - 1) / cap);
            const int sum0 = Sx0 + Sb0;
            const int St = ((sum0 + 63) / 64) * 64;
            int Sx = (int)(((long long)St * Sx0 + sum0 / 2) / sum0);
            if (Sx < Sx0) Sx = Sx0;
            int Sb = St - Sx;
            if (Sb < Sb0) { Sb = Sb0; Sx = St - Sb; }

            proj_slab<<<KGC * (Sx + Sb), TPB, 0, stream>>>(
                img, Px, xlors, ylors, zlors, center, size_, perm, part,
                nx, ny, nz, Sx, Sb);
            finalize_kernel<<<(ntot + 255) / 256, 256, 0, stream>>>(
                xlors, ylors, zlors, size_, perm, part, out, nx, ny, nz, G);
        } else {
            const int nbx = (nx + 7) / 8;
            const int nby = (ny + 7) / 8;
            const int nbz = (nz + 7) / 8;
            proj_coop<<<nbx + nby + nbz, 256, 0, stream>>>(
                img, Px, xlors, ylors, zlors, center, size_, perm, out,
                nx, ny, nz, nbx, nby, G);
        }
    } else {
        const int nbx = (nx + 255) / 256;
        const int nby = (ny + 255) / 256;
        const int nbz = (nz + 255) / 256;
        proj_fallback<<<nbx + nby + nbz, 256, 0, stream>>>(
            img, xlors, ylors, zlors, center, size_, out,
            nx, ny, nz, nbx, nby, G);
    }
}

// Round 17
// 361.330 us; speedup vs baseline: 1.8705x; 1.2593x over previous
//
#include <hip/hip_runtime.h>
#include <math.h>

// KERNEL_WIDTH = sqrt(9/pi) = 1.6925687506432297
#define KW2_F  2.8647889756541161f   // (9/pi)
#define KW_INV 0.5908179502964271f   // 1/KW
#define RW_F   1.6926f               // slightly >= KW (safe superset bound)

#define TPB      1024   // slab-kernel block size (2 blocks/CU -> 32 waves/CU)
#define MAXL     4      // LORs per thread (cap 4096/block -> grid packs 3x512)
#define KG       16     // k-slices per block
#define KGC      8      // 128 / KG
#define TROW     132    // 128+4: float4-aligned staging; measured best conflicts

typedef __attribute__((ext_vector_type(2))) float f2;

__device__ __forceinline__ float fast_sqrtf(float x) {
    return __builtin_amdgcn_sqrtf(x);   // raw v_sqrt_f32, ~1 ulp
}

// weight pair: w = max(0, 1 - sqrt(d2)/KW), elementwise on 2 taps
__device__ __forceinline__ f2 wpair(f2 d2) {
    f2 s;
    s.x = fast_sqrtf(d2.x);
    s.y = fast_sqrtf(d2.y);
    f2 w = 1.0f - s * KW_INV;
    w.x = fmaxf(w.x, 0.0f);
    w.y = fmaxf(w.y, 0.0f);
    return w;
}

// ---------------------------------------------------------------------------
// Slab projection kernel. G == 128 only (gated on host). NO LOR sort: since
// taps come from LDS, lane order only affects bank conflicts, which measure
// at the random-address statistical floor with or without sorting (R15/R16).
// LOR reads in natural order are perfectly coalesced.
//
// Geometry:
//   x-set: walks orig axis1; u = orig0 (L[1],L[4]), v = orig2 (L[0],L[3]).
//          Slab = image[:, k, :] (rows of 512 B, coalesced).
//   y-set: walks orig axis2; u = orig0 (L[1],L[4]), v = orig1 (L[0],L[3]).
//   z-set: walks orig axis2; u = orig0 (L[0],L[3]), v = orig1 (L[1],L[4]).
//          y/z slab = Px[k] plane (contiguous 64 KB).
//
// Inner loop: FIXED 4x4 window at (ceil(u-RW), ceil(v-RW)); w>0 disk diameter
// 2*KW = 3.385 < 4 -> covers every reference tap with w>0; w clamps at 0 for
// the rest -> identical sum. Tap (3,3) is provably w==0 and skipped -> 15
// taps. With this problem's LOR extents (transverse endpoints within +-60 of
// center, G=128) every (LOR,k) window is interior: u in [3.5,123.5] ->
// ulo in [2,122] (edge path kept only as a safety net).
// Output: per-k-group partial sums to [KGC][ntot] (coalesced), reduced by
// finalize_kernel (deterministic).
// ---------------------------------------------------------------------------
__global__ __launch_bounds__(TPB, 2)
void proj_slab(const float* __restrict__ img,
               const float* __restrict__ Px,
               const float* __restrict__ xl,
               const float* __restrict__ yl,
               const float* __restrict__ zl,
               const float* __restrict__ center,
               const float* __restrict__ size_,
               float* __restrict__ partial,
               int nx, int ny, int nz, int Sx, int Sb)
{
    const int G = 128, G2 = 128 * 128;
    __shared__ float tile[128 * TROW];   // 67.6 KB -> 2 blocks/CU

    const int b   = blockIdx.x;
    const int tid = threadIdx.x;
    const int nB  = ny + nz;
    const int ntot = nx + nB;

    int kg, lo, hi, isA;
    if (b < KGC * Sx) {
        isA = 1; kg = b / Sx;
        const int sp = b % Sx;
        const int c  = (nx + Sx - 1) / Sx;
        lo = sp * c; hi = min(nx, lo + c);
    } else {
        isA = 0;
        const int bb = b - KGC * Sx;
        kg = bb / Sb;
        const int sp = bb % Sb;
        const int c  = (nB + Sb - 1) / Sb;
        lo = sp * c; hi = min(nB, lo + c);
    }
    const int k0 = kg * KG;

    // block-uniform geometry (au = 0 for all sets)
    const int av = isA ? 2 : 1;
    const int aw = isA ? 1 : 2;
    const float vsu = size_[0] / (float)G, inv_vsu = 1.0f / vsu;
    const float vsv = size_[av] / (float)G, inv_vsv = 1.0f / vsv;
    const float vsw = size_[aw] / (float)G;
    const float luo = center[0]  - 0.5f * size_[0];
    const float lvo = center[av] - 0.5f * size_[av];
    const float wlo = center[aw] - 0.5f * size_[aw];

    float fu0[MAXL], fv0[MAXL], duk[MAXL], dvk[MAXL], acc[MAXL];

#pragma unroll
    for (int l = 0; l < MAXL; ++l) {
        const int idx = lo + tid + l * TPB;
        acc[l] = 0.0f;
        if (idx < hi) {
            const float* L;
            float pu1, pu2, pv1, pv2;
            if (isA) {
                L = xl + 6 * (size_t)idx;
                pu1 = L[1]; pu2 = L[4]; pv1 = L[0]; pv2 = L[3];
            } else if (idx < ny) {
                L = yl + 6 * (size_t)idx;
                pu1 = L[1]; pu2 = L[4]; pv1 = L[0]; pv2 = L[3];
            } else {
                L = zl + 6 * (size_t)(idx - ny);
                pu1 = L[0]; pu2 = L[3]; pv1 = L[1]; pv2 = L[4];
            }
            const float pw1 = L[2], pw2 = L[5];
            const float inv_dw = 1.0f / (pw2 - pw1);
            const float dt = vsw * inv_dw;
            const float t0 = (wlo + 0.5f * vsw - pw1) * inv_dw;
            const float dU = pu2 - pu1, dV = pv2 - pv1;
            fu0[l] = (fmaf(t0, dU, pu1) - luo) * inv_vsu - 0.5f;
            fv0[l] = (fmaf(t0, dV, pv1) - lvo) * inv_vsv - 0.5f;
            duk[l] = dt * dU * inv_vsu;
            dvk[l] = dt * dV * inv_vsv;
        } else {
            fu0[l] = -1e9f; fv0[l] = -1e9f; duk[l] = 0.0f; dvk[l] = 0.0f;
        }
    }

    for (int kk = k0; kk < k0 + KG; ++kk) {
        __syncthreads();   // previous iteration's reads done before overwrite
        if (isA) {
#pragma unroll
            for (int it = 0; it < 4; ++it) {
                const int f = (tid + it * TPB) * 4;   // float index in plane
                const int r = f >> 7, c = f & 127;
                const float4 v = *reinterpret_cast<const float4*>(
                    img + (size_t)r * G2 + kk * G + c);
                *reinterpret_cast<float4*>(tile + r * TROW + c) = v;
            }
        } else {
#pragma unroll
            for (int it = 0; it < 4; ++it) {
                const int f = (tid + it * TPB) * 4;
                const int r = f >> 7, c = f & 127;
                const float4 v = *reinterpret_cast<const float4*>(
                    Px + (size_t)kk * G2 + f);
                *reinterpret_cast<float4*>(tile + r * TROW + c) = v;
            }
        }
        __syncthreads();

        const float fk = (float)kk;
#pragma unroll
        for (int l = 0; l < MAXL; ++l) {
            const float u = fmaf(fk, duk[l], fu0[l]);
            const float v = fmaf(fk, dvk[l], fv0[l]);
            const float fulo = ceilf(u - RW_F);
            const float fvlo = ceilf(v - RW_F);
            const int ulo = (int)fulo;
            const int vlo = (int)fvlo;
            float a = acc[l];
            if ((unsigned)ulo <= 124u && (unsigned)vlo <= 124u) {
                // interior fast path: straight-line 15 taps, uniform lanes
                const float du0 = fulo - u, dv0 = fvlo - v;
                float du2[4], dv2[4];
#pragma unroll
                for (int r = 0; r < 4; ++r) {
                    const float dr = du0 + (float)r; du2[r] = dr * dr;
                    const float dc = dv0 + (float)r; dv2[r] = dc * dc;
                }
                const float* tp = tile + (ulo * TROW + vlo);
                f2 accp = {0.0f, 0.0f};
#pragma unroll
                for (int r = 0; r < 3; ++r) {
                    const f2 d2a = {du2[r] + dv2[0], du2[r] + dv2[1]};
                    const f2 d2b = {du2[r] + dv2[2], du2[r] + dv2[3]};
                    const f2 wa = wpair(d2a);
                    const f2 wb = wpair(d2b);
                    const f2 va = {tp[r * TROW + 0], tp[r * TROW + 1]};
                    const f2 vb = {tp[r * TROW + 2], tp[r * TROW + 3]};
                    accp += wa * va;
                    accp += wb * vb;
                }
                {   // row 3: taps (3,0),(3,1),(3,2); (3,3) provably w==0
                    const f2 d2a = {du2[3] + dv2[0], du2[3] + dv2[1]};
                    const f2 wa = wpair(d2a);
                    const f2 va = {tp[3 * TROW + 0], tp[3 * TROW + 1]};
                    accp += wa * va;
                    const float d2c = du2[3] + dv2[2];
                    const float wc =
                        fmaxf(0.0f, fmaf(-fast_sqrtf(d2c), KW_INV, 1.0f));
                    a = fmaf(wc, tp[3 * TROW + 2], a);
                }
                acc[l] = a + accp.x + accp.y;
            } else if (u > -RW_F && u < 127.0f + RW_F &&
                       v > -RW_F && v < 127.0f + RW_F) {
                // edge path: safety net (unreachable for this problem's LORs)
#pragma unroll
                for (int r = 0; r < 4; ++r) {
                    const int ju = ulo + r;
                    const float dd = (float)ju - u;
                    const float dd2 = dd * dd;
                    const int rb = min(max(ju, 0), 127) * TROW;
                    const bool rok = (unsigned)ju < 128u;
#pragma unroll
                    for (int c = 0; c < 4; ++c) {
                        const int jv = vlo + c;
                        const float dvv = (float)jv - v;
                        const float d2 = fmaf(dvv, dvv, dd2);
                        float w =
                            fmaxf(0.0f, fmaf(-fast_sqrtf(d2), KW_INV, 1.0f));
                        if (!(rok && (unsigned)jv < 128u)) w = 0.0f;
                        a = fmaf(w, tile[rb + min(max(jv, 0), 127)], a);
                    }
                }
                acc[l] = a;
            }
        }
    }

#pragma unroll
    for (int l = 0; l < MAXL; ++l) {
        const int idx = lo + tid + l * TPB;
        if (idx < hi) {
            const int sidx = isA ? idx : nx + idx;
            partial[(size_t)kg * ntot + sidx] = acc[l];
        }
    }
}

// Finalize: sum KGC partials, apply step. Natural order: out[t] directly.
__global__ __launch_bounds__(256)
void finalize_kernel(const float* __restrict__ xl,
                     const float* __restrict__ yl,
                     const float* __restrict__ zl,
                     const float* __restrict__ size_,
                     const float* __restrict__ partial,
                     float* __restrict__ out,
                     int nx, int ny, int nz, int G)
{
    const int t = blockIdx.x * 256 + threadIdx.x;
    const int ntot = nx + ny + nz;
    if (t >= ntot) return;

    const float* L; float vsw;
    if (t < nx)           { L = xl + 6 * (size_t)t;              vsw = size_[1] / (float)G; }
    else if (t < nx + ny) { L = yl + 6 * (size_t)(t - nx);       vsw = size_[2] / (float)G; }
    else                  { L = zl + 6 * (size_t)(t - nx - ny);  vsw = size_[2] / (float)G; }

    float s = 0.0f;
#pragma unroll
    for (int kg = 0; kg < KGC; ++kg) s += partial[(size_t)kg * ntot + t];

    const float dx = L[3] - L[0], dy = L[4] - L[1], dz = L[5] - L[2];
    const float len = sqrtf(dx * dx + dy * dy + dz * dz);
    out[t] = s * vsw * len / fabsf(dz);
}

// ---------------------------------------------------------------------------
// Middle-tier fallback (cooperative gather path): 32 lanes per LOR,
// natural order.
// ---------------------------------------------------------------------------
__device__ __forceinline__
float tor_chunk(const float* __restrict__ img,
                float fx0, float fy0, float dfx, float dfy,
                int k0, int n0, int n1, int s0, int s1)
{
    float fx[4], fy[4];
#pragma unroll
    for (int j = 0; j < 4; ++j) {
        fx[j] = fmaf((float)(k0 + j), dfx, fx0);
        fy[j] = fmaf((float)(k0 + j), dfy, fy0);
    }
    const float fxmin = fminf(fx[0], fx[3]), fxmax = fmaxf(fx[0], fx[3]);
    const float fymin = fminf(fy[0], fy[3]), fymax = fmaxf(fy[0], fy[3]);
    const int xlo = max(0,      (int)ceilf (fxmin - RW_F));
    const int xhi = min(n0 - 1, (int)floorf(fxmax + RW_F));

    float acc0 = 0.0f, acc1 = 0.0f, acc2 = 0.0f, acc3 = 0.0f;
    const float* rowp = img + xlo * s0 + k0;
    for (int jx = xlo; jx <= xhi; ++jx, rowp += s0) {
        float ddx2[4];
#pragma unroll
        for (int j = 0; j < 4; ++j) {
            const float dxx = (float)jx - fx[j];
            ddx2[j] = dxx * dxx;
        }
        const float rowmin =
            fminf(fminf(ddx2[0], ddx2[1]), fminf(ddx2[2], ddx2[3]));
        const float rad = fast_sqrtf(fmaxf(KW2_F - rowmin, 0.0f));
        const int ylo = max(0,      (int)ceilf (fymin - rad));
        const int yhi = min(n1 - 1, (int)floorf(fymax + rad));

        const float* p = rowp + ylo * s1;
        for (int jy = ylo; jy <= yhi; ++jy, p += s1) {
            const float4 v = *reinterpret_cast<const float4*>(p);
            float wg[4];
#pragma unroll
            for (int j = 0; j < 4; ++j) {
                const float dyy = (float)jy - fy[j];
                const float d2  = fmaf(dyy, dyy, ddx2[j]);
                wg[j] = fmaxf(0.0f, fmaf(-fast_sqrtf(d2), KW_INV, 1.0f));
            }
            acc0 = fmaf(wg[0], v.x, acc0);
            acc1 = fmaf(wg[1], v.y, acc1);
            acc2 = fmaf(wg[2], v.z, acc2);
            acc3 = fmaf(wg[3], v.w, acc3);
        }
    }
    return (acc0 + acc1) + (acc2 + acc3);
}

__global__ __launch_bounds__(256)
void proj_coop(const float* __restrict__ imgZ,
               const float* __restrict__ imgX,
               const float* __restrict__ xlp,
               const float* __restrict__ ylp,
               const float* __restrict__ zlp,
               const float* __restrict__ center,
               const float* __restrict__ size_,
               float* __restrict__ out,
               int nx, int ny, int nz,
               int nbx, int nby, int G)
{
    const int b = blockIdx.x;
    const int G2 = G * G;
    const int sub  = threadIdx.x >> 5;
    const int lane = threadIdx.x & 31;

    const float* img; const float* lors; float* op;
    int a0, a1, a2, s0, s1;

    if (b < nbx) {
        const int i = b * 8 + sub; if (i >= nx) return;
        img = imgX; lors = xlp + 6 * (size_t)i;  op = out + i;
        a0 = 2; a1 = 0; a2 = 1;  s0 = G2; s1 = G;
    } else if (b < nbx + nby) {
        const int i = (b - nbx) * 8 + sub; if (i >= ny) return;
        img = imgZ; lors = ylp + 6 * (size_t)i;  op = out + nx + i;
        a0 = 1; a1 = 0; a2 = 2;  s0 = G; s1 = G2;
    } else {
        const int i = (b - nbx - nby) * 8 + sub; if (i >= nz) return;
        img = imgZ; lors = zlp + 6 * (size_t)i;  op = out + nx + ny + i;
        a0 = 0; a1 = 1; a2 = 2;  s0 = G2; s1 = G;
    }

    const float S0 = size_[a0], S1 = size_[a1], S2 = size_[a2];
    const float vs0 = S0 / (float)G, vs1 = S1 / (float)G, vs2 = S2 / (float)G;
    const float lo0 = center[a0] - 0.5f * S0;
    const float lo1 = center[a1] - 0.5f * S1;
    const float lo2 = center[a2] - 0.5f * S2;
    const float inv_vs0 = 1.0f / vs0, inv_vs1 = 1.0f / vs1;

    const float p1x = lors[0], p1y = lors[1], p1z = lors[2];
    const float p2x = lors[3], p2y = lors[4], p2z = lors[5];
    const float dx = p2x - p1x, dy = p2y - p1y, dz = p2z - p1z;
    const float len = sqrtf(dx * dx + dy * dy + dz * dz);
    const float inv_dz = 1.0f / dz;
    const float step = vs2 * len * fabsf(inv_dz);

    const float t0  = (lo2 + 0.5f * vs2 - p1z) * inv_dz;
    const float dt  = vs2 * inv_dz;
    const float fx0 = (fmaf(t0, dx, p1x) - lo0) * inv_vs0 - 0.5f;
    const float fy0 = (fmaf(t0, dy, p1y) - lo1) * inv_vs1 - 0.5f;
    const float dfx = dt * dx * inv_vs0;
    const float dfy = dt * dy * inv_vs1;

    float partialv = 0.0f;
    const int nchunks = G >> 2;
    for (int c = lane; c < nchunks; c += 32)
        partialv += tor_chunk(img, fx0, fy0, dfx, dfy, 4 * c, G, G, s0, s1);

#pragma unroll
    for (int m = 16; m >= 1; m >>= 1)
        partialv += __shfl_xor(partialv, m);

    if (lane == 0) *op = partialv * step;
}

// Scalar fallback (any G), one thread per LOR.
__device__ __forceinline__
float tor_lor_s(const float* __restrict__ img,
                const float* __restrict__ L,
                float lo0, float lo1, float lo2,
                float vs0, float vs1, float vs2,
                int n0, int n1, int n2, int s0, int s1, int s2)
{
    const float inv_vs0 = 1.0f / vs0, inv_vs1 = 1.0f / vs1;
    const float p1x = L[0], p1y = L[1], p1z = L[2];
    const float p2x = L[3], p2y = L[4], p2z = L[5];
    const float dx = p2x - p1x, dy = p2y - p1y, dz = p2z - p1z;
    const float len = sqrtf(dx * dx + dy * dy + dz * dz);
    const float inv_dz = 1.0f / dz;
    const float step = vs2 * len * fabsf(inv_dz);

    float acc_total = 0.0f;
    for (int k = 0; k < n2; ++k) {
        const float zc = lo2 + ((float)k + 0.5f) * vs2;
        const float t  = (zc - p1z) * inv_dz;
        const float fx = (fmaf(t, dx, p1x) - lo0) * inv_vs0 - 0.5f;
        const float fy = (fmaf(t, dy, p1y) - lo1) * inv_vs1 - 0.5f;
        const int ix = (int)rintf(fx);
        const int iy = (int)rintf(fy);
        const int kb = k * s2;
        float acc = 0.0f;
#pragma unroll
        for (int o0 = -2; o0 <= 2; ++o0) {
            const int jx = ix + o0;
            if ((unsigned)jx >= (unsigned)n0) continue;
            const float dxx  = (float)jx - fx;
            const float ddx2 = dxx * dxx;
            if (ddx2 >= KW2_F) continue;
            const int xb = jx * s0 + kb;
#pragma unroll
            for (int o1 = -2; o1 <= 2; ++o1) {
                const int jy = iy + o1;
                if ((unsigned)jy >= (unsigned)n1) continue;
                const float dyy = (float)jy - fy;
                const float d2  = fmaf(dyy, dyy, ddx2);
                if (d2 < KW2_F) {
                    const float w = fmaf(-fast_sqrtf(d2), KW_INV, 1.0f);
                    acc = fmaf(w, img[xb + jy * s1], acc);
                }
            }
        }
        acc_total += acc;
    }
    return acc_total * step;
}

__global__ __launch_bounds__(256)
void proj_fallback(const float* __restrict__ img,
                   const float* __restrict__ xlp,
                   const float* __restrict__ ylp,
                   const float* __restrict__ zlp,
                   const float* __restrict__ center,
                   const float* __restrict__ size_,
                   float* __restrict__ out,
                   int nx, int ny, int nz,
                   int nbx, int nby, int G)
{
    const int b = blockIdx.x;
    const int G2 = G * G;
    const float* lors; float* op;
    int a0, a1, a2, s0, s1, s2;

    if (b < nbx) {
        const int i = b * 256 + threadIdx.x; if (i >= nx) return;
        lors = xlp + 6 * (size_t)i;  op = out + i;
        a0 = 2; a1 = 0; a2 = 1;  s0 = 1; s1 = G2; s2 = G;
    } else if (b < nbx + nby) {
        const int i = (b - nbx) * 256 + threadIdx.x; if (i >= ny) return;
        lors = ylp + 6 * (size_t)i;  op = out + nx + i;
        a0 = 1; a1 = 0; a2 = 2;  s0 = G; s1 = G2; s2 = 1;
    } else {
        const int i = (b - nbx - nby) * 256 + threadIdx.x; if (i >= nz) return;
        lors = zlp + 6 * (size_t)i;  op = out + nx + ny + i;
        a0 = 0; a1 = 1; a2 = 2;  s0 = G2; s1 = G; s2 = 1;
    }

    const float S0 = size_[a0], S1 = size_[a1], S2 = size_[a2];
    const float vs0 = S0 / (float)G, vs1 = S1 / (float)G, vs2 = S2 / (float)G;
    *op = tor_lor_s(img, lors,
                    center[a0] - 0.5f * S0, center[a1] - 0.5f * S1,
                    center[a2] - 0.5f * S2,
                    vs0, vs1, vs2, G, G, G, s0, s1, s2);
}

// 2D transpose in[R][C] -> out[C][R]; Px[a,i0,i1] = image[i0,i1,a].
__global__ __launch_bounds__(256)
void transpose_RC(const float* __restrict__ in, float* __restrict__ outp,
                  int R, int C)
{
    __shared__ float tile[32][33];
    const int rt = blockIdx.x * 32;
    const int ct = blockIdx.y * 32;
    const int tx = threadIdx.x;
    const int ty = threadIdx.y;   // block (32,8)
#pragma unroll
    for (int j = 0; j < 32; j += 8)
        tile[ty + j][tx] = in[(size_t)(rt + ty + j) * C + (ct + tx)];
    __syncthreads();
#pragma unroll
    for (int j = 0; j < 32; j += 8)
        outp[(size_t)(ct + ty + j) * R + (rt + tx)] = tile[tx][ty + j];
}

extern "C" void kernel_launch(void* const* d_in, const int* in_sizes, int n_in,
                              void* d_out, int out_size, void* d_ws, size_t ws_size,
                              hipStream_t stream)
{
    const float* img    = (const float*)d_in[0];
    const float* center = (const float*)d_in[2];
    const float* size_  = (const float*)d_in[3];
    const float* xlors  = (const float*)d_in[4];
    const float* ylors  = (const float*)d_in[5];
    const float* zlors  = (const float*)d_in[6];
    float* out = (float*)d_out;

    const int nx = in_sizes[4] / 6;
    const int ny = in_sizes[5] / 6;
    const int nz = in_sizes[6] / 6;
    const int nB   = ny + nz;
    const int ntot = nx + nB;

    int G = (int)lround(cbrt((double)in_sizes[0]));
    const int G2 = G * G;

    // Workspace: [Px G^3 f32][partial KGC*ntot f32]
    const size_t pxBytes  = (size_t)G * G2 * sizeof(float);
    const size_t needSlab = pxBytes + (size_t)KGC * ntot * sizeof(float);
    const size_t needCoop = pxBytes;

    const bool slab = (G == 128) && (ws_size >= needSlab);
    const bool coop = !slab && (G % 32 == 0) && (ws_size >= needCoop);

    if (slab || coop) {
        float* Px   = (float*)d_ws;
        float* part = (float*)((char*)d_ws + pxBytes);

        transpose_RC<<<dim3(G2 / 32, G / 32), dim3(32, 8), 0, stream>>>(
            img, Px, G2, G);

        if (slab) {
            // Pack the grid into full scheduling rounds: 2 blocks/CU x 256 CU
            // = 512 resident slots; make KGC*(Sx+Sb) a multiple of 512, i.e.
            // Sx+Sb a multiple of 64, with uniform chunks <= TPB*MAXL.
            const int cap = TPB * MAXL;
            int Sx0 = max(1, (nx + cap - 1) / cap);
            int Sb0 = max(1, (nB + cap - 1) / cap);
            const int sum0 = Sx0 + Sb0;
            const int St = ((sum0 + 63) / 64) * 64;
            int Sx = (int)(((long long)St * Sx0 + sum0 / 2) / sum0);
            if (Sx < Sx0) Sx = Sx0;
            int Sb = St - Sx;
            if (Sb < Sb0) { Sb = Sb0; Sx = St - Sb; }

            proj_slab<<<KGC * (Sx + Sb), TPB, 0, stream>>>(
                img, Px, xlors, ylors, zlors, center, size_, part,
                nx, ny, nz, Sx, Sb);
            finalize_kernel<<<(ntot + 255) / 256, 256, 0, stream>>>(
                xlors, ylors, zlors, size_, part, out, nx, ny, nz, G);
        } else {
            const int nbx = (nx + 7) / 8;
            const int nby = (ny + 7) / 8;
            const int nbz = (nz + 7) / 8;
            proj_coop<<<nbx + nby + nbz, 256, 0, stream>>>(
                img, Px, xlors, ylors, zlors, center, size_, out,
                nx, ny, nz, nbx, nby, G);
        }
    } else {
        const int nbx = (nx + 255) / 256;
        const int nby = (ny + 255) / 256;
        const int nbz = (nz + 255) / 256;
        proj_fallback<<<nbx + nby + nbz, 256, 0, stream>>>(
            img, xlors, ylors, zlors, center, size_, out,
            nx, ny, nz, nbx, nby, G);
    }
}